// Round 1
// baseline (1093.266 us; speedup 1.0000x reference)
//
#include <hip/hip_runtime.h>

// Linear RNN scan: h_t = h_{t-1}@A + x_t@B ; y_t = h_t@C
// B=8, S=4096, IN=STATE=OUT=256.  All f32.
// 3-phase chunked scan: local prefix scans (64 chunks x 64 steps),
// carry scan over chunk boundaries with A^64, carry application, then y GEMM.
//
// Workspace layout (floats):
//   U/P   : [S][B][N]  = 8388608 floats (32 MiB)   in-place u -> local prefix -> h
//   pw0   : 65536 floats (A-power ping)
//   pw1   : 65536 floats (A-power pong; ends holding A^64)
//   Hc    : [C][B][N]  = 131072 floats (chunk incoming states)
// total ~33 MB

#define SEQ    4096
#define NBATCH 8
#define ND     256
#define CHUNK  64
#define NCHUNK 64

// ---------- dense 256x256 GEMM: Out = X @ Y (row-major) ----------
__global__ __launch_bounds__(256) void gemm256(const float* __restrict__ X,
                                               const float* __restrict__ Y,
                                               float* __restrict__ Out) {
  const int m0 = blockIdx.x * 4;     // 64 blocks x 4 rows
  const int n  = threadIdx.x;
  __shared__ float Xs[ND][4];        // Xs[k][r] = X[m0+r][k]
  #pragma unroll
  for (int r = 0; r < 4; ++r) Xs[n][r] = X[(m0 + r) * ND + n];
  __syncthreads();
  float a0 = 0.f, a1 = 0.f, a2 = 0.f, a3 = 0.f;
  #pragma unroll 8
  for (int k = 0; k < ND; ++k) {
    const float yv = Y[k * ND + n];
    const float4 xv = *(const float4*)&Xs[k][0];
    a0 = fmaf(xv.x, yv, a0);
    a1 = fmaf(xv.y, yv, a1);
    a2 = fmaf(xv.z, yv, a2);
    a3 = fmaf(xv.w, yv, a3);
  }
  Out[(m0 + 0) * ND + n] = a0;
  Out[(m0 + 1) * ND + n] = a1;
  Out[(m0 + 2) * ND + n] = a2;
  Out[(m0 + 3) * ND + n] = a3;
}

// ---------- U[s][b][n] = sum_i x[b][s][i] * B[i][n] ----------
__global__ __launch_bounds__(256) void xb_gemm(const float* __restrict__ x,
                                               const float* __restrict__ Bm,
                                               float* __restrict__ U) {
  const int b  = blockIdx.x >> 8;
  const int st = blockIdx.x & 255;
  const int s0 = st * 16;
  const int t  = threadIdx.x;        // n
  __shared__ float xs[ND][16];       // xs[i][r] = x[b][s0+r][i]
  #pragma unroll
  for (int r = 0; r < 16; ++r)
    xs[t][r] = x[((size_t)b * SEQ + s0 + r) * ND + t];
  __syncthreads();
  float acc[16];
  #pragma unroll
  for (int r = 0; r < 16; ++r) acc[r] = 0.f;
  #pragma unroll 4
  for (int k = 0; k < ND; ++k) {
    const float bv = Bm[k * ND + t];
    const float4 x0 = *(const float4*)&xs[k][0];
    const float4 x1 = *(const float4*)&xs[k][4];
    const float4 x2 = *(const float4*)&xs[k][8];
    const float4 x3 = *(const float4*)&xs[k][12];
    acc[0]  = fmaf(x0.x, bv, acc[0]);
    acc[1]  = fmaf(x0.y, bv, acc[1]);
    acc[2]  = fmaf(x0.z, bv, acc[2]);
    acc[3]  = fmaf(x0.w, bv, acc[3]);
    acc[4]  = fmaf(x1.x, bv, acc[4]);
    acc[5]  = fmaf(x1.y, bv, acc[5]);
    acc[6]  = fmaf(x1.z, bv, acc[6]);
    acc[7]  = fmaf(x1.w, bv, acc[7]);
    acc[8]  = fmaf(x2.x, bv, acc[8]);
    acc[9]  = fmaf(x2.y, bv, acc[9]);
    acc[10] = fmaf(x2.z, bv, acc[10]);
    acc[11] = fmaf(x2.w, bv, acc[11]);
    acc[12] = fmaf(x3.x, bv, acc[12]);
    acc[13] = fmaf(x3.y, bv, acc[13]);
    acc[14] = fmaf(x3.z, bv, acc[14]);
    acc[15] = fmaf(x3.w, bv, acc[15]);
  }
  #pragma unroll
  for (int r = 0; r < 16; ++r)
    U[((size_t)(s0 + r) * NBATCH + b) * ND + t] = acc[r];
}

// ---------- per-chunk local prefix scan: p_j = p_{j-1}@A + u_j (in place) ----------
__global__ __launch_bounds__(512) void scan_local(const float* __restrict__ A,
                                                  float* __restrict__ P) {
  const int c = blockIdx.x;                 // chunk
  const int n = threadIdx.x & 255;
  const int g = threadIdx.x >> 8;           // batch group (4 batches)
  __shared__ float hT[ND][NBATCH];          // hT[k][b]
  *(float4*)&hT[n][4 * g] = make_float4(0.f, 0.f, 0.f, 0.f);
  __syncthreads();
  for (int j = 0; j < CHUNK; ++j) {
    const size_t t = (size_t)c * CHUNK + j;
    float* Pt = P + t * (NBATCH * ND) + (size_t)(4 * g) * ND + n;
    float a0 = Pt[0];
    float a1 = Pt[ND];
    float a2 = Pt[2 * ND];
    float a3 = Pt[3 * ND];
    #pragma unroll 8
    for (int k = 0; k < ND; ++k) {
      const float av = A[k * ND + n];
      const float4 hv = *(const float4*)&hT[k][4 * g];
      a0 = fmaf(hv.x, av, a0);
      a1 = fmaf(hv.y, av, a1);
      a2 = fmaf(hv.z, av, a2);
      a3 = fmaf(hv.w, av, a3);
    }
    __syncthreads();
    *(float4*)&hT[n][4 * g] = make_float4(a0, a1, a2, a3);
    Pt[0]      = a0;
    Pt[ND]     = a1;
    Pt[2 * ND] = a2;
    Pt[3 * ND] = a3;
    __syncthreads();
  }
}

// ---------- carry scan over chunk boundaries: H_{c+1} = H_c@A64 + P_end(c) ----------
__global__ __launch_bounds__(256) void scan_carry(const float* __restrict__ A64,
                                                  const float* __restrict__ P,
                                                  const float* __restrict__ h0,
                                                  float* __restrict__ Hc) {
  const int b = blockIdx.x;                 // batch
  const int n = threadIdx.x;
  __shared__ float H[ND];
  float hv = h0[n];
  H[n] = hv;
  Hc[(size_t)b * ND + n] = hv;              // Hc[0][b][n]
  __syncthreads();
  for (int c = 0; c < NCHUNK - 1; ++c) {
    const size_t tend = (size_t)c * CHUNK + CHUNK - 1;
    float acc = P[tend * (NBATCH * ND) + (size_t)b * ND + n];
    #pragma unroll 4
    for (int k = 0; k < ND; k += 4) {
      const float4 hk = *(const float4*)&H[k];
      acc = fmaf(hk.x, A64[(k + 0) * ND + n], acc);
      acc = fmaf(hk.y, A64[(k + 1) * ND + n], acc);
      acc = fmaf(hk.z, A64[(k + 2) * ND + n], acc);
      acc = fmaf(hk.w, A64[(k + 3) * ND + n], acc);
    }
    __syncthreads();
    H[n] = acc;
    Hc[((size_t)(c + 1) * NBATCH + b) * ND + n] = acc;
    __syncthreads();
  }
}

// ---------- apply carry inside chunk: g_j = g_{j-1}@A, h_j = g_j + p_j ----------
__global__ __launch_bounds__(512) void scan_apply(const float* __restrict__ A,
                                                  const float* __restrict__ Hc,
                                                  float* __restrict__ P) {
  const int c = blockIdx.x;
  const int n = threadIdx.x & 255;
  const int g = threadIdx.x >> 8;
  __shared__ float hT[ND][NBATCH];          // hT[k][b] holds carry g
  #pragma unroll
  for (int bb = 0; bb < 4; ++bb)
    hT[n][4 * g + bb] = Hc[((size_t)c * NBATCH + 4 * g + bb) * ND + n];
  __syncthreads();
  for (int j = 0; j < CHUNK; ++j) {
    const size_t t = (size_t)c * CHUNK + j;
    float* Pt = P + t * (NBATCH * ND) + (size_t)(4 * g) * ND + n;
    float p0 = Pt[0];
    float p1 = Pt[ND];
    float p2 = Pt[2 * ND];
    float p3 = Pt[3 * ND];
    float g0 = 0.f, g1 = 0.f, g2 = 0.f, g3 = 0.f;
    #pragma unroll 8
    for (int k = 0; k < ND; ++k) {
      const float av = A[k * ND + n];
      const float4 hv = *(const float4*)&hT[k][4 * g];
      g0 = fmaf(hv.x, av, g0);
      g1 = fmaf(hv.y, av, g1);
      g2 = fmaf(hv.z, av, g2);
      g3 = fmaf(hv.w, av, g3);
    }
    __syncthreads();
    *(float4*)&hT[n][4 * g] = make_float4(g0, g1, g2, g3);   // carry only
    Pt[0]      = p0 + g0;                                    // h = p + g
    Pt[ND]     = p1 + g1;
    Pt[2 * ND] = p2 + g2;
    Pt[3 * ND] = p3 + g3;
    __syncthreads();
  }
}

// ---------- y[b][s][o] = sum_n h[s][b][n] * C[n][o] ----------
__global__ __launch_bounds__(256) void y_gemm(const float* __restrict__ P,
                                              const float* __restrict__ Cm,
                                              float* __restrict__ y) {
  const int b  = blockIdx.x >> 8;
  const int st = blockIdx.x & 255;
  const int s0 = st * 16;
  const int t  = threadIdx.x;        // o
  __shared__ float hs[ND][16];       // hs[n][r] = h[s0+r][b][n]
  #pragma unroll
  for (int r = 0; r < 16; ++r)
    hs[t][r] = P[((size_t)(s0 + r) * NBATCH + b) * ND + t];
  __syncthreads();
  float acc[16];
  #pragma unroll
  for (int r = 0; r < 16; ++r) acc[r] = 0.f;
  #pragma unroll 4
  for (int k = 0; k < ND; ++k) {
    const float cv = Cm[k * ND + t];
    const float4 h0 = *(const float4*)&hs[k][0];
    const float4 h1 = *(const float4*)&hs[k][4];
    const float4 h2 = *(const float4*)&hs[k][8];
    const float4 h3 = *(const float4*)&hs[k][12];
    acc[0]  = fmaf(h0.x, cv, acc[0]);
    acc[1]  = fmaf(h0.y, cv, acc[1]);
    acc[2]  = fmaf(h0.z, cv, acc[2]);
    acc[3]  = fmaf(h0.w, cv, acc[3]);
    acc[4]  = fmaf(h1.x, cv, acc[4]);
    acc[5]  = fmaf(h1.y, cv, acc[5]);
    acc[6]  = fmaf(h1.z, cv, acc[6]);
    acc[7]  = fmaf(h1.w, cv, acc[7]);
    acc[8]  = fmaf(h2.x, cv, acc[8]);
    acc[9]  = fmaf(h2.y, cv, acc[9]);
    acc[10] = fmaf(h2.z, cv, acc[10]);
    acc[11] = fmaf(h2.w, cv, acc[11]);
    acc[12] = fmaf(h3.x, cv, acc[12]);
    acc[13] = fmaf(h3.y, cv, acc[13]);
    acc[14] = fmaf(h3.z, cv, acc[14]);
    acc[15] = fmaf(h3.w, cv, acc[15]);
  }
  #pragma unroll
  for (int r = 0; r < 16; ++r)
    y[((size_t)b * SEQ + s0 + r) * ND + t] = acc[r];
}

extern "C" void kernel_launch(void* const* d_in, const int* in_sizes, int n_in,
                              void* d_out, int out_size, void* d_ws, size_t ws_size,
                              hipStream_t stream) {
  const float* x  = (const float*)d_in[0];
  const float* A  = (const float*)d_in[1];
  const float* Bm = (const float*)d_in[2];
  const float* Cm = (const float*)d_in[3];
  const float* h0 = (const float*)d_in[4];
  float* y = (float*)d_out;

  float* U   = (float*)d_ws;                         // SEQ*NBATCH*ND
  float* pw0 = U + (size_t)SEQ * NBATCH * ND;        // A-power ping
  float* pw1 = pw0 + ND * ND;                        // A-power pong
  float* Hc  = pw1 + ND * ND;                        // NCHUNK*NBATCH*ND

  // Phase 0: input projection, time-major
  xb_gemm<<<NBATCH * 256, 256, 0, stream>>>(x, Bm, U);

  // A^64 by repeated squaring (ends in pw1)
  gemm256<<<64, 256, 0, stream>>>(A,   A,   pw0);    // A^2
  gemm256<<<64, 256, 0, stream>>>(pw0, pw0, pw1);    // A^4
  gemm256<<<64, 256, 0, stream>>>(pw1, pw1, pw0);    // A^8
  gemm256<<<64, 256, 0, stream>>>(pw0, pw0, pw1);    // A^16
  gemm256<<<64, 256, 0, stream>>>(pw1, pw1, pw0);    // A^32
  gemm256<<<64, 256, 0, stream>>>(pw0, pw0, pw1);    // A^64

  // Phase 1: local prefix scans within each chunk (in place on U)
  scan_local<<<NCHUNK, 512, 0, stream>>>(A, U);

  // Phase 2: sequential carry scan across chunks (per batch)
  scan_carry<<<NBATCH, 256, 0, stream>>>(pw1, U, h0, Hc);

  // Phase 3: propagate carries through chunks; U becomes h
  scan_apply<<<NCHUNK, 512, 0, stream>>>(A, Hc, U);

  // Phase 4: output projection
  y_gemm<<<NBATCH * 256, 256, 0, stream>>>(U, Cm, y);
}

// Round 2
// 574.971 us; speedup vs baseline: 1.9014x; 1.9014x over previous
//
#include <hip/hip_runtime.h>

// Linear RNN scan: h_t = h_{t-1}@A + x_t@B ; y_t = h_t@C
// B=8, S=4096, IN=STATE=OUT=256.  All f32.
// Two-level chunked scan:
//   level-1 chunks of 16 steps (256 chunks), level-2 groups of 16 chunks (16 groups).
//   chunk_end: per-chunk local scan (final state only)          256 blk x 16 steps
//   carry_collect: per-group scan of chunk-ends with A^16        128 blk x 16 steps
//   top_scan: scan over 16 group-carries with A^256                8 blk x 16 steps
//   carry_scan2: materialize all 256 chunk-entry states          128 blk x 16 steps
//   scan_final: re-run local scan from true entry state          256 blk x 16 steps
//
// Workspace (floats):
//   U    [S][B][N]        8M   (u -> h in place)
//   t0,t1,A16,A256        4 x 64K
//   E    [256][B][N]      512K
//   S    [16][B][N]       32K
//   G    [16][B][N]       32K
//   Hc   [256][B][N]      512K

#define SEQ    4096
#define NBATCH 8
#define ND     256
#define CHUNK  16
#define NCHUNK 256
#define NGROUP 16

// ---------- dense 256x256 GEMM: Out = X @ Y (row-major) ----------
__global__ __launch_bounds__(256) void gemm256(const float* __restrict__ X,
                                               const float* __restrict__ Y,
                                               float* __restrict__ Out) {
  const int m0 = blockIdx.x * 4;     // 64 blocks x 4 rows
  const int n  = threadIdx.x;
  __shared__ float Xs[ND][4];
  #pragma unroll
  for (int r = 0; r < 4; ++r) Xs[n][r] = X[(m0 + r) * ND + n];
  __syncthreads();
  float a0 = 0.f, a1 = 0.f, a2 = 0.f, a3 = 0.f;
  #pragma unroll 8
  for (int k = 0; k < ND; ++k) {
    const float yv = Y[k * ND + n];
    const float4 xv = *(const float4*)&Xs[k][0];
    a0 = fmaf(xv.x, yv, a0);
    a1 = fmaf(xv.y, yv, a1);
    a2 = fmaf(xv.z, yv, a2);
    a3 = fmaf(xv.w, yv, a3);
  }
  Out[(m0 + 0) * ND + n] = a0;
  Out[(m0 + 1) * ND + n] = a1;
  Out[(m0 + 2) * ND + n] = a2;
  Out[(m0 + 3) * ND + n] = a3;
}

// ---------- U[s][b][n] = sum_i x[b][s][i] * B[i][n] ----------
__global__ __launch_bounds__(256) void xb_gemm(const float* __restrict__ x,
                                               const float* __restrict__ Bm,
                                               float* __restrict__ U) {
  const int b  = blockIdx.x >> 8;
  const int st = blockIdx.x & 255;
  const int s0 = st * 16;
  const int t  = threadIdx.x;        // n
  __shared__ float xs[ND][16];
  #pragma unroll
  for (int r = 0; r < 16; ++r)
    xs[t][r] = x[((size_t)b * SEQ + s0 + r) * ND + t];
  __syncthreads();
  float acc[16];
  #pragma unroll
  for (int r = 0; r < 16; ++r) acc[r] = 0.f;
  #pragma unroll 4
  for (int k = 0; k < ND; ++k) {
    const float bv = Bm[k * ND + t];
    const float4 x0 = *(const float4*)&xs[k][0];
    const float4 x1 = *(const float4*)&xs[k][4];
    const float4 x2 = *(const float4*)&xs[k][8];
    const float4 x3 = *(const float4*)&xs[k][12];
    acc[0]  = fmaf(x0.x, bv, acc[0]);
    acc[1]  = fmaf(x0.y, bv, acc[1]);
    acc[2]  = fmaf(x0.z, bv, acc[2]);
    acc[3]  = fmaf(x0.w, bv, acc[3]);
    acc[4]  = fmaf(x1.x, bv, acc[4]);
    acc[5]  = fmaf(x1.y, bv, acc[5]);
    acc[6]  = fmaf(x1.z, bv, acc[6]);
    acc[7]  = fmaf(x1.w, bv, acc[7]);
    acc[8]  = fmaf(x2.x, bv, acc[8]);
    acc[9]  = fmaf(x2.y, bv, acc[9]);
    acc[10] = fmaf(x2.z, bv, acc[10]);
    acc[11] = fmaf(x2.w, bv, acc[11]);
    acc[12] = fmaf(x3.x, bv, acc[12]);
    acc[13] = fmaf(x3.y, bv, acc[13]);
    acc[14] = fmaf(x3.z, bv, acc[14]);
    acc[15] = fmaf(x3.w, bv, acc[15]);
  }
  #pragma unroll
  for (int r = 0; r < 16; ++r)
    U[((size_t)(s0 + r) * NBATCH + b) * ND + t] = acc[r];
}

// ---------- per-chunk local scan from zero; store ONLY final state E[c] ----------
__global__ __launch_bounds__(512) void chunk_end(const float* __restrict__ A,
                                                 const float* __restrict__ U,
                                                 float* __restrict__ E) {
  const int c = blockIdx.x;
  const int n = threadIdx.x & 255;
  const int g = threadIdx.x >> 8;           // 4 batches per group
  __shared__ float hT[ND][NBATCH];
  *(float4*)&hT[n][4 * g] = make_float4(0.f, 0.f, 0.f, 0.f);
  __syncthreads();
  float a0, a1, a2, a3;
  for (int j = 0; j < CHUNK; ++j) {
    const float* Ut = U + ((size_t)(c * CHUNK + j) * NBATCH + 4 * g) * ND + n;
    a0 = Ut[0];
    a1 = Ut[ND];
    a2 = Ut[2 * ND];
    a3 = Ut[3 * ND];
    #pragma unroll 8
    for (int k = 0; k < ND; ++k) {
      const float av = A[k * ND + n];
      const float4 hv = *(const float4*)&hT[k][4 * g];
      a0 = fmaf(hv.x, av, a0);
      a1 = fmaf(hv.y, av, a1);
      a2 = fmaf(hv.z, av, a2);
      a3 = fmaf(hv.w, av, a3);
    }
    __syncthreads();
    *(float4*)&hT[n][4 * g] = make_float4(a0, a1, a2, a3);
    __syncthreads();
  }
  E[((size_t)c * NBATCH + 4 * g + 0) * ND + n] = a0;
  E[((size_t)c * NBATCH + 4 * g + 1) * ND + n] = a1;
  E[((size_t)c * NBATCH + 4 * g + 2) * ND + n] = a2;
  E[((size_t)c * NBATCH + 4 * g + 3) * ND + n] = a3;
}

// ---------- per-group scan of E with multiplier A16; store ONLY final S[g] ----------
__global__ __launch_bounds__(256) void carry_collect(const float* __restrict__ A16,
                                                     const float* __restrict__ E,
                                                     float* __restrict__ S) {
  const int g = blockIdx.x >> 3;
  const int b = blockIdx.x & 7;
  const int n = threadIdx.x;
  __shared__ float H[ND];
  H[n] = 0.f;
  __syncthreads();
  float acc = 0.f;
  for (int j = 0; j < NGROUP; ++j) {
    const int c = g * NGROUP + j;
    acc = E[((size_t)c * NBATCH + b) * ND + n];
    #pragma unroll 4
    for (int k = 0; k < ND; k += 4) {
      const float4 hk = *(const float4*)&H[k];
      acc = fmaf(hk.x, A16[(k + 0) * ND + n], acc);
      acc = fmaf(hk.y, A16[(k + 1) * ND + n], acc);
      acc = fmaf(hk.z, A16[(k + 2) * ND + n], acc);
      acc = fmaf(hk.w, A16[(k + 3) * ND + n], acc);
    }
    __syncthreads();
    H[n] = acc;
    __syncthreads();
  }
  S[((size_t)g * NBATCH + b) * ND + n] = acc;
}

// ---------- top scan over 16 groups with A256: G[g+1] = G[g]@A256 + S[g] ----------
__global__ __launch_bounds__(256) void top_scan(const float* __restrict__ A256,
                                                const float* __restrict__ S,
                                                const float* __restrict__ h0,
                                                float* __restrict__ G) {
  const int b = blockIdx.x;
  const int n = threadIdx.x;
  __shared__ float H[ND];
  float hv = h0[n];
  H[n] = hv;
  G[(size_t)b * ND + n] = hv;               // G[0]
  __syncthreads();
  for (int g = 0; g < NGROUP - 1; ++g) {
    float acc = S[((size_t)g * NBATCH + b) * ND + n];
    #pragma unroll 4
    for (int k = 0; k < ND; k += 4) {
      const float4 hk = *(const float4*)&H[k];
      acc = fmaf(hk.x, A256[(k + 0) * ND + n], acc);
      acc = fmaf(hk.y, A256[(k + 1) * ND + n], acc);
      acc = fmaf(hk.z, A256[(k + 2) * ND + n], acc);
      acc = fmaf(hk.w, A256[(k + 3) * ND + n], acc);
    }
    __syncthreads();
    H[n] = acc;
    G[((size_t)(g + 1) * NBATCH + b) * ND + n] = acc;
    __syncthreads();
  }
}

// ---------- materialize all chunk-entry states Hc[c] within each group ----------
__global__ __launch_bounds__(256) void carry_scan2(const float* __restrict__ A16,
                                                   const float* __restrict__ E,
                                                   const float* __restrict__ G,
                                                   float* __restrict__ Hc) {
  const int g = blockIdx.x >> 3;
  const int b = blockIdx.x & 7;
  const int n = threadIdx.x;
  __shared__ float H[ND];
  float acc = G[((size_t)g * NBATCH + b) * ND + n];
  H[n] = acc;
  Hc[((size_t)(g * NGROUP) * NBATCH + b) * ND + n] = acc;
  __syncthreads();
  for (int j = 0; j < NGROUP - 1; ++j) {
    const int c = g * NGROUP + j;
    acc = E[((size_t)c * NBATCH + b) * ND + n];
    #pragma unroll 4
    for (int k = 0; k < ND; k += 4) {
      const float4 hk = *(const float4*)&H[k];
      acc = fmaf(hk.x, A16[(k + 0) * ND + n], acc);
      acc = fmaf(hk.y, A16[(k + 1) * ND + n], acc);
      acc = fmaf(hk.z, A16[(k + 2) * ND + n], acc);
      acc = fmaf(hk.w, A16[(k + 3) * ND + n], acc);
    }
    __syncthreads();
    H[n] = acc;
    Hc[((size_t)(c + 1) * NBATCH + b) * ND + n] = acc;
    __syncthreads();
  }
}

// ---------- final local scan from true entry state; h overwrites U ----------
__global__ __launch_bounds__(512) void scan_final(const float* __restrict__ A,
                                                  const float* __restrict__ Hc,
                                                  float* __restrict__ U) {
  const int c = blockIdx.x;
  const int n = threadIdx.x & 255;
  const int g = threadIdx.x >> 8;
  __shared__ float hT[ND][NBATCH];
  {
    float h0v = Hc[((size_t)c * NBATCH + 4 * g + 0) * ND + n];
    float h1v = Hc[((size_t)c * NBATCH + 4 * g + 1) * ND + n];
    float h2v = Hc[((size_t)c * NBATCH + 4 * g + 2) * ND + n];
    float h3v = Hc[((size_t)c * NBATCH + 4 * g + 3) * ND + n];
    *(float4*)&hT[n][4 * g] = make_float4(h0v, h1v, h2v, h3v);
  }
  __syncthreads();
  for (int j = 0; j < CHUNK; ++j) {
    float* Ut = U + ((size_t)(c * CHUNK + j) * NBATCH + 4 * g) * ND + n;
    float a0 = Ut[0];
    float a1 = Ut[ND];
    float a2 = Ut[2 * ND];
    float a3 = Ut[3 * ND];
    #pragma unroll 8
    for (int k = 0; k < ND; ++k) {
      const float av = A[k * ND + n];
      const float4 hv = *(const float4*)&hT[k][4 * g];
      a0 = fmaf(hv.x, av, a0);
      a1 = fmaf(hv.y, av, a1);
      a2 = fmaf(hv.z, av, a2);
      a3 = fmaf(hv.w, av, a3);
    }
    __syncthreads();
    *(float4*)&hT[n][4 * g] = make_float4(a0, a1, a2, a3);
    Ut[0]      = a0;
    Ut[ND]     = a1;
    Ut[2 * ND] = a2;
    Ut[3 * ND] = a3;
    __syncthreads();
  }
}

// ---------- y[b][s][o] = sum_n h[s][b][n] * C[n][o] ----------
__global__ __launch_bounds__(256) void y_gemm(const float* __restrict__ P,
                                              const float* __restrict__ Cm,
                                              float* __restrict__ y) {
  const int b  = blockIdx.x >> 8;
  const int st = blockIdx.x & 255;
  const int s0 = st * 16;
  const int t  = threadIdx.x;        // o
  __shared__ float hs[ND][16];
  #pragma unroll
  for (int r = 0; r < 16; ++r)
    hs[t][r] = P[((size_t)(s0 + r) * NBATCH + b) * ND + t];
  __syncthreads();
  float acc[16];
  #pragma unroll
  for (int r = 0; r < 16; ++r) acc[r] = 0.f;
  #pragma unroll 4
  for (int k = 0; k < ND; ++k) {
    const float cv = Cm[k * ND + t];
    const float4 h0 = *(const float4*)&hs[k][0];
    const float4 h1 = *(const float4*)&hs[k][4];
    const float4 h2 = *(const float4*)&hs[k][8];
    const float4 h3 = *(const float4*)&hs[k][12];
    acc[0]  = fmaf(h0.x, cv, acc[0]);
    acc[1]  = fmaf(h0.y, cv, acc[1]);
    acc[2]  = fmaf(h0.z, cv, acc[2]);
    acc[3]  = fmaf(h0.w, cv, acc[3]);
    acc[4]  = fmaf(h1.x, cv, acc[4]);
    acc[5]  = fmaf(h1.y, cv, acc[5]);
    acc[6]  = fmaf(h1.z, cv, acc[6]);
    acc[7]  = fmaf(h1.w, cv, acc[7]);
    acc[8]  = fmaf(h2.x, cv, acc[8]);
    acc[9]  = fmaf(h2.y, cv, acc[9]);
    acc[10] = fmaf(h2.z, cv, acc[10]);
    acc[11] = fmaf(h2.w, cv, acc[11]);
    acc[12] = fmaf(h3.x, cv, acc[12]);
    acc[13] = fmaf(h3.y, cv, acc[13]);
    acc[14] = fmaf(h3.z, cv, acc[14]);
    acc[15] = fmaf(h3.w, cv, acc[15]);
  }
  #pragma unroll
  for (int r = 0; r < 16; ++r)
    y[((size_t)b * SEQ + s0 + r) * ND + t] = acc[r];
}

extern "C" void kernel_launch(void* const* d_in, const int* in_sizes, int n_in,
                              void* d_out, int out_size, void* d_ws, size_t ws_size,
                              hipStream_t stream) {
  const float* x  = (const float*)d_in[0];
  const float* A  = (const float*)d_in[1];
  const float* Bm = (const float*)d_in[2];
  const float* Cm = (const float*)d_in[3];
  const float* h0 = (const float*)d_in[4];
  float* y = (float*)d_out;

  float* U    = (float*)d_ws;                       // 8M floats
  float* t0   = U + (size_t)SEQ * NBATCH * ND;      // 64K
  float* t1   = t0 + ND * ND;                       // 64K
  float* A16  = t1 + ND * ND;                       // 64K
  float* A256 = A16 + ND * ND;                      // 64K
  float* E    = A256 + ND * ND;                     // 512K
  float* Sg   = E + (size_t)NCHUNK * NBATCH * ND;   // 32K
  float* G    = Sg + NGROUP * NBATCH * ND;          // 32K
  float* Hc   = G + NGROUP * NBATCH * ND;           // 512K

  // Phase 0: input projection, time-major
  xb_gemm<<<NBATCH * 256, 256, 0, stream>>>(x, Bm, U);

  // A powers: A16 and A256 by repeated squaring
  gemm256<<<64, 256, 0, stream>>>(A,   A,   t0);    // A^2
  gemm256<<<64, 256, 0, stream>>>(t0,  t0,  t1);    // A^4
  gemm256<<<64, 256, 0, stream>>>(t1,  t1,  t0);    // A^8
  gemm256<<<64, 256, 0, stream>>>(t0,  t0,  A16);   // A^16
  gemm256<<<64, 256, 0, stream>>>(A16, A16, t0);    // A^32
  gemm256<<<64, 256, 0, stream>>>(t0,  t0,  t1);    // A^64
  gemm256<<<64, 256, 0, stream>>>(t1,  t1,  t0);    // A^128
  gemm256<<<64, 256, 0, stream>>>(t0,  t0,  A256);  // A^256

  // Phase 1: per-chunk local scan ends
  chunk_end<<<NCHUNK, 512, 0, stream>>>(A, U, E);

  // Phase 2: per-group carry collection (multiplier A^16)
  carry_collect<<<NGROUP * NBATCH, 256, 0, stream>>>(A16, E, Sg);

  // Phase 3: top-level scan over groups (multiplier A^256)
  top_scan<<<NBATCH, 256, 0, stream>>>(A256, Sg, h0, G);

  // Phase 4: materialize all chunk-entry states
  carry_scan2<<<NGROUP * NBATCH, 256, 0, stream>>>(A16, E, G, Hc);

  // Phase 5: final scan from true entry states; U becomes h
  scan_final<<<NCHUNK, 512, 0, stream>>>(A, Hc, U);

  // Phase 6: output projection
  y_gemm<<<NBATCH * 256, 256, 0, stream>>>(U, Cm, y);
}

// Round 3
// 434.724 us; speedup vs baseline: 2.5149x; 1.3226x over previous
//
#include <hip/hip_runtime.h>

// Linear RNN scan: h_t = h_{t-1}@A + x_t@B ; y_t = h_t@C
// B=8, S=4096, IN=STATE=OUT=256.
// MFMA (16x16x32 f16) with 2-term split-f16 (hi + 2048*lo), f32 accumulate:
//   rel err ~2^-22 per product; random-walk over 4096 steps ~1e-5 << 4.96e-4.
// Phases:
//   prep_frags: pack A,B,C into MFMA B-operand fragment arrays (hi/lo f16)
//   mfma_gemm mode0: U[s*8+b][n] = x @ B
//   gemm256 x8 (f32): A^16, A^256 for carry scans
//   mfma_scan mode0: per-chunk (16 steps) final states E  (h in swizzled LDS)
//   carry_collect / top_scan / carry_scan2 (f32): chunk entry states Hc
//   mfma_scan mode1: final scan from Hc, writes h over U
//   mfma_gemm mode1: y = h @ C

#define SEQ    4096
#define NBATCH 8
#define ND     256
#define CHUNK  16
#define NCHUNK 256
#define NGROUP 16
#define LOSC   2048.0f
#define LOINV  (1.0f/2048.0f)

typedef _Float16 fp16_t;
typedef __attribute__((ext_vector_type(8))) _Float16 f16x8;
typedef __attribute__((ext_vector_type(4))) float f32x4;

// ---------- pack one 256x256 f32 matrix into B-operand frag arrays ----------
// frag linear index: ((tile*8 + slice)*64 + lane)*8 + j
// value = M[k][n], k = slice*32 + (lane>>4)*8 + j, n = tile*16 + (lane&15)
__global__ __launch_bounds__(64) void prep_frags(const float* __restrict__ M,
                                                 fp16_t* __restrict__ hi,
                                                 fp16_t* __restrict__ lo) {
  const int blk  = blockIdx.x;       // tile*8 + slice
  const int lane = threadIdx.x;
  const int tile = blk >> 3, slice = blk & 7;
  const int n  = tile * 16 + (lane & 15);
  const int k0 = slice * 32 + (lane >> 4) * 8;
  f16x8 vh, vl;
  #pragma unroll
  for (int j = 0; j < 8; ++j) {
    const float v = M[(size_t)(k0 + j) * ND + n];
    const fp16_t h = (fp16_t)v;
    vh[j] = h;
    vl[j] = (fp16_t)((v - (float)h) * LOSC);
  }
  const size_t fo = ((size_t)blk * 64 + lane) * 8;
  *(f16x8*)&hi[fo] = vh;
  *(f16x8*)&lo[fo] = vl;
}

// ---------- MFMA GEMM: Out[m][n] = X[m][:] @ M, M-rows m = s*8+b ----------
// mode 0 (xb): X indexed [b][s][i] (in-row remap), Out direct [m]
// mode 1 (y):  X direct [m], Out remapped to [b][s][o]
__global__ __launch_bounds__(512) void mfma_gemm(const float* __restrict__ X,
                                                 const fp16_t* __restrict__ Mhi,
                                                 const fp16_t* __restrict__ Mlo,
                                                 float* __restrict__ Out,
                                                 int mode) {
  const int m0   = blockIdx.x * 16;
  const int tid  = threadIdx.x;
  const int lane = tid & 63;
  const int w    = tid >> 6;         // wave 0..7, owns N-tiles 2w, 2w+1
  const int arow = lane & 15;
  const int akg  = lane >> 4;
  const int crow0 = (lane >> 4) * 4;
  const int ccol  = lane & 15;

  // resident B-operand fragments
  f16x8 BH[2][8], BL[2][8];
  #pragma unroll
  for (int t2 = 0; t2 < 2; ++t2) {
    #pragma unroll
    for (int s = 0; s < 8; ++s) {
      const size_t fo = (((size_t)(2 * w + t2) * 8 + s) * 64 + lane) * 8;
      BH[t2][s] = *(const f16x8*)&Mhi[fo];
      BL[t2][s] = *(const f16x8*)&Mlo[fo];
    }
  }

  const int m_in = m0 + arow;
  const size_t in_row = (mode == 0)
      ? ((size_t)(m_in & 7) * SEQ + (m_in >> 3))   // x[b][s][:]
      : (size_t)m_in;                               // U[m][:]

  f32x4 accm[2], accl[2];
  #pragma unroll
  for (int t2 = 0; t2 < 2; ++t2) {
    accm[t2] = (f32x4)0.0f;
    accl[t2] = (f32x4)0.0f;
  }

  #pragma unroll
  for (int s = 0; s < 8; ++s) {
    const float* xp = &X[in_row * ND + s * 32 + akg * 8];
    const float4 x0 = *(const float4*)(xp);
    const float4 x1 = *(const float4*)(xp + 4);
    float xv[8] = {x0.x, x0.y, x0.z, x0.w, x1.x, x1.y, x1.z, x1.w};
    f16x8 ah, al;
    #pragma unroll
    for (int j = 0; j < 8; ++j) {
      const fp16_t h = (fp16_t)xv[j];
      ah[j] = h;
      al[j] = (fp16_t)((xv[j] - (float)h) * LOSC);
    }
    #pragma unroll
    for (int t2 = 0; t2 < 2; ++t2) {
      accm[t2] = __builtin_amdgcn_mfma_f32_16x16x32_f16(ah, BH[t2][s], accm[t2], 0, 0, 0);
      accl[t2] = __builtin_amdgcn_mfma_f32_16x16x32_f16(ah, BL[t2][s], accl[t2], 0, 0, 0);
      accl[t2] = __builtin_amdgcn_mfma_f32_16x16x32_f16(al, BH[t2][s], accl[t2], 0, 0, 0);
    }
  }

  #pragma unroll
  for (int t2 = 0; t2 < 2; ++t2) {
    #pragma unroll
    for (int r = 0; r < 4; ++r) {
      const int row = crow0 + r;
      const int m   = m0 + row;
      const size_t out_row = (mode == 1)
          ? ((size_t)(m & 7) * SEQ + (m >> 3))      // y[b][s][:]
          : (size_t)m;                               // U[m][:]
      const float v = accm[t2][r] + accl[t2][r] * LOINV;
      Out[out_row * ND + (2 * w + t2) * 16 + ccol] = v;
    }
  }
}

// ---------- MFMA chunk scan ----------
// mode 0: h starts 0, write only final state E[c]
// mode 1: h starts Hc[c], write h over U each step
__global__ __launch_bounds__(512) void mfma_scan(const fp16_t* __restrict__ Ahi,
                                                 const fp16_t* __restrict__ Alo,
                                                 const float* __restrict__ Hc,
                                                 float* __restrict__ U,
                                                 float* __restrict__ E,
                                                 int mode) {
  const int c    = blockIdx.x;
  const int tid  = threadIdx.x;
  const int lane = tid & 63;
  const int w    = tid >> 6;
  const int arow = lane & 15;
  const int akg  = lane >> 4;
  const int crow0 = (lane >> 4) * 4;
  const int ccol  = lane & 15;

  __shared__ fp16_t hH[16 * ND];   // [16 rows][256 cols], XOR-swizzled
  __shared__ fp16_t hL[16 * ND];
  char* hHb = (char*)hH;
  char* hLb = (char*)hL;

  // prologue: init h rows 0..7 (Hc or 0), rows 8..15 zero
  {
    const int row  = tid >> 5;           // 0..15
    const int col0 = (tid & 31) * 8;
    float v[8];
    if (mode == 1 && row < 8) {
      const float4 p0 = *(const float4*)&Hc[((size_t)c * NBATCH + row) * ND + col0];
      const float4 p1 = *(const float4*)&Hc[((size_t)c * NBATCH + row) * ND + col0 + 4];
      v[0] = p0.x; v[1] = p0.y; v[2] = p0.z; v[3] = p0.w;
      v[4] = p1.x; v[5] = p1.y; v[6] = p1.z; v[7] = p1.w;
    } else {
      #pragma unroll
      for (int j = 0; j < 8; ++j) v[j] = 0.f;
    }
    f16x8 vh, vl;
    #pragma unroll
    for (int j = 0; j < 8; ++j) {
      const fp16_t h = (fp16_t)v[j];
      vh[j] = h;
      vl[j] = (fp16_t)((v[j] - (float)h) * LOSC);
    }
    const int byte = (row * 512 + col0 * 2) ^ ((row & 7) << 4);
    *(f16x8*)(hHb + byte) = vh;
    *(f16x8*)(hLb + byte) = vl;
  }

  // resident A-matrix fragments (B-operand)
  f16x8 BH[2][8], BL[2][8];
  #pragma unroll
  for (int t2 = 0; t2 < 2; ++t2) {
    #pragma unroll
    for (int s = 0; s < 8; ++s) {
      const size_t fo = (((size_t)(2 * w + t2) * 8 + s) * 64 + lane) * 8;
      BH[t2][s] = *(const f16x8*)&Ahi[fo];
      BL[t2][s] = *(const f16x8*)&Alo[fo];
    }
  }
  __syncthreads();

  f32x4 res[2];
  for (int j = 0; j < CHUNK; ++j) {
    const size_t t = (size_t)c * CHUNK + j;
    // C-init = u_t (f32 exact)
    f32x4 accm[2], accl[2];
    #pragma unroll
    for (int t2 = 0; t2 < 2; ++t2) {
      #pragma unroll
      for (int r = 0; r < 4; ++r) {
        const int row = crow0 + r;
        accm[t2][r] = (row < 8)
            ? U[(t * NBATCH + row) * ND + (2 * w + t2) * 16 + ccol] : 0.f;
      }
      accl[t2] = (f32x4)0.0f;
    }
    // h @ A over K=256
    #pragma unroll
    for (int s = 0; s < 8; ++s) {
      const int byte = (arow * 512 + s * 64 + akg * 16) ^ ((arow & 7) << 4);
      const f16x8 ah = *(const f16x8*)(hHb + byte);
      const f16x8 al = *(const f16x8*)(hLb + byte);
      #pragma unroll
      for (int t2 = 0; t2 < 2; ++t2) {
        accm[t2] = __builtin_amdgcn_mfma_f32_16x16x32_f16(ah, BH[t2][s], accm[t2], 0, 0, 0);
        accl[t2] = __builtin_amdgcn_mfma_f32_16x16x32_f16(ah, BL[t2][s], accl[t2], 0, 0, 0);
        accl[t2] = __builtin_amdgcn_mfma_f32_16x16x32_f16(al, BH[t2][s], accl[t2], 0, 0, 0);
      }
    }
    #pragma unroll
    for (int t2 = 0; t2 < 2; ++t2) {
      #pragma unroll
      for (int r = 0; r < 4; ++r)
        res[t2][r] = accm[t2][r] + accl[t2][r] * LOINV;
    }
    __syncthreads();   // all reads of old h done
    // write new h (rows>=8 write zeros), optionally store to U
    #pragma unroll
    for (int t2 = 0; t2 < 2; ++t2) {
      #pragma unroll
      for (int r = 0; r < 4; ++r) {
        const int row = crow0 + r;
        const int col = (2 * w + t2) * 16 + ccol;
        const float v = res[t2][r];
        const fp16_t vh = (fp16_t)v;
        const fp16_t vl = (fp16_t)((v - (float)vh) * LOSC);
        const int byte = (row * 512 + col * 2) ^ ((row & 7) << 4);
        *(fp16_t*)(hHb + byte) = vh;
        *(fp16_t*)(hLb + byte) = vl;
        if (mode == 1 && row < 8)
          U[(t * NBATCH + row) * ND + col] = v;
      }
    }
    __syncthreads();
  }

  if (mode == 0) {
    #pragma unroll
    for (int t2 = 0; t2 < 2; ++t2) {
      #pragma unroll
      for (int r = 0; r < 4; ++r) {
        const int row = crow0 + r;
        if (row < 8)
          E[((size_t)c * NBATCH + row) * ND + (2 * w + t2) * 16 + ccol] = res[t2][r];
      }
    }
  }
}

// ---------- dense 256x256 f32 GEMM (A-power chain) ----------
__global__ __launch_bounds__(256) void gemm256(const float* __restrict__ X,
                                               const float* __restrict__ Y,
                                               float* __restrict__ Out) {
  const int m0 = blockIdx.x * 4;
  const int n  = threadIdx.x;
  __shared__ float Xs[ND][4];
  #pragma unroll
  for (int r = 0; r < 4; ++r) Xs[n][r] = X[(m0 + r) * ND + n];
  __syncthreads();
  float a0 = 0.f, a1 = 0.f, a2 = 0.f, a3 = 0.f;
  #pragma unroll 8
  for (int k = 0; k < ND; ++k) {
    const float yv = Y[k * ND + n];
    const float4 xv = *(const float4*)&Xs[k][0];
    a0 = fmaf(xv.x, yv, a0);
    a1 = fmaf(xv.y, yv, a1);
    a2 = fmaf(xv.z, yv, a2);
    a3 = fmaf(xv.w, yv, a3);
  }
  Out[(m0 + 0) * ND + n] = a0;
  Out[(m0 + 1) * ND + n] = a1;
  Out[(m0 + 2) * ND + n] = a2;
  Out[(m0 + 3) * ND + n] = a3;
}

// ---------- per-group scan of E with A16; final S[g] only ----------
__global__ __launch_bounds__(256) void carry_collect(const float* __restrict__ A16,
                                                     const float* __restrict__ E,
                                                     float* __restrict__ S) {
  const int g = blockIdx.x >> 3;
  const int b = blockIdx.x & 7;
  const int n = threadIdx.x;
  __shared__ float H[ND];
  H[n] = 0.f;
  __syncthreads();
  float acc = 0.f;
  for (int j = 0; j < NGROUP; ++j) {
    const int c = g * NGROUP + j;
    acc = E[((size_t)c * NBATCH + b) * ND + n];
    #pragma unroll 4
    for (int k = 0; k < ND; k += 4) {
      const float4 hk = *(const float4*)&H[k];
      acc = fmaf(hk.x, A16[(k + 0) * ND + n], acc);
      acc = fmaf(hk.y, A16[(k + 1) * ND + n], acc);
      acc = fmaf(hk.z, A16[(k + 2) * ND + n], acc);
      acc = fmaf(hk.w, A16[(k + 3) * ND + n], acc);
    }
    __syncthreads();
    H[n] = acc;
    __syncthreads();
  }
  S[((size_t)g * NBATCH + b) * ND + n] = acc;
}

// ---------- top scan over 16 groups with A256 ----------
__global__ __launch_bounds__(256) void top_scan(const float* __restrict__ A256,
                                                const float* __restrict__ S,
                                                const float* __restrict__ h0,
                                                float* __restrict__ G) {
  const int b = blockIdx.x;
  const int n = threadIdx.x;
  __shared__ float H[ND];
  float hv = h0[n];
  H[n] = hv;
  G[(size_t)b * ND + n] = hv;
  __syncthreads();
  for (int g = 0; g < NGROUP - 1; ++g) {
    float acc = S[((size_t)g * NBATCH + b) * ND + n];
    #pragma unroll 4
    for (int k = 0; k < ND; k += 4) {
      const float4 hk = *(const float4*)&H[k];
      acc = fmaf(hk.x, A256[(k + 0) * ND + n], acc);
      acc = fmaf(hk.y, A256[(k + 1) * ND + n], acc);
      acc = fmaf(hk.z, A256[(k + 2) * ND + n], acc);
      acc = fmaf(hk.w, A256[(k + 3) * ND + n], acc);
    }
    __syncthreads();
    H[n] = acc;
    G[((size_t)(g + 1) * NBATCH + b) * ND + n] = acc;
    __syncthreads();
  }
}

// ---------- materialize all chunk-entry states ----------
__global__ __launch_bounds__(256) void carry_scan2(const float* __restrict__ A16,
                                                   const float* __restrict__ E,
                                                   const float* __restrict__ G,
                                                   float* __restrict__ Hc) {
  const int g = blockIdx.x >> 3;
  const int b = blockIdx.x & 7;
  const int n = threadIdx.x;
  __shared__ float H[ND];
  float acc = G[((size_t)g * NBATCH + b) * ND + n];
  H[n] = acc;
  Hc[((size_t)(g * NGROUP) * NBATCH + b) * ND + n] = acc;
  __syncthreads();
  for (int j = 0; j < NGROUP - 1; ++j) {
    const int c = g * NGROUP + j;
    acc = E[((size_t)c * NBATCH + b) * ND + n];
    #pragma unroll 4
    for (int k = 0; k < ND; k += 4) {
      const float4 hk = *(const float4*)&H[k];
      acc = fmaf(hk.x, A16[(k + 0) * ND + n], acc);
      acc = fmaf(hk.y, A16[(k + 1) * ND + n], acc);
      acc = fmaf(hk.z, A16[(k + 2) * ND + n], acc);
      acc = fmaf(hk.w, A16[(k + 3) * ND + n], acc);
    }
    __syncthreads();
    H[n] = acc;
    Hc[((size_t)(c + 1) * NBATCH + b) * ND + n] = acc;
    __syncthreads();
  }
}

extern "C" void kernel_launch(void* const* d_in, const int* in_sizes, int n_in,
                              void* d_out, int out_size, void* d_ws, size_t ws_size,
                              hipStream_t stream) {
  const float* x  = (const float*)d_in[0];
  const float* A  = (const float*)d_in[1];
  const float* Bm = (const float*)d_in[2];
  const float* Cm = (const float*)d_in[3];
  const float* h0 = (const float*)d_in[4];
  float* y = (float*)d_out;

  float* U    = (float*)d_ws;                       // 8M floats
  float* t0   = U + (size_t)SEQ * NBATCH * ND;      // 65536
  float* t1   = t0 + ND * ND;
  float* A16  = t1 + ND * ND;
  float* A256 = A16 + ND * ND;
  float* E    = A256 + ND * ND;                     // 524288
  float* Sg   = E + (size_t)NCHUNK * NBATCH * ND;   // 32768
  float* G    = Sg + NGROUP * NBATCH * ND;          // 32768
  float* Hc   = G + NGROUP * NBATCH * ND;           // 524288
  fp16_t* fA_hi = (fp16_t*)(Hc + (size_t)NCHUNK * NBATCH * ND);
  fp16_t* fA_lo = fA_hi + ND * ND;
  fp16_t* fB_hi = fA_lo + ND * ND;
  fp16_t* fB_lo = fB_hi + ND * ND;
  fp16_t* fC_hi = fB_lo + ND * ND;
  fp16_t* fC_lo = fC_hi + ND * ND;

  // pack matrices into fragment arrays
  prep_frags<<<128, 64, 0, stream>>>(A,  fA_hi, fA_lo);
  prep_frags<<<128, 64, 0, stream>>>(Bm, fB_hi, fB_lo);
  prep_frags<<<128, 64, 0, stream>>>(Cm, fC_hi, fC_lo);

  // U = x @ B (time-major rows m = s*8+b)
  mfma_gemm<<<2048, 512, 0, stream>>>(x, fB_hi, fB_lo, U, 0);

  // A powers (f32)
  gemm256<<<64, 256, 0, stream>>>(A,   A,   t0);    // A^2
  gemm256<<<64, 256, 0, stream>>>(t0,  t0,  t1);    // A^4
  gemm256<<<64, 256, 0, stream>>>(t1,  t1,  t0);    // A^8
  gemm256<<<64, 256, 0, stream>>>(t0,  t0,  A16);   // A^16
  gemm256<<<64, 256, 0, stream>>>(A16, A16, t0);    // A^32
  gemm256<<<64, 256, 0, stream>>>(t0,  t0,  t1);    // A^64
  gemm256<<<64, 256, 0, stream>>>(t1,  t1,  t0);    // A^128
  gemm256<<<64, 256, 0, stream>>>(t0,  t0,  A256);  // A^256

  // chunk local ends
  mfma_scan<<<NCHUNK, 512, 0, stream>>>(fA_hi, fA_lo, Hc, U, E, 0);

  // carry hierarchy (f32)
  carry_collect<<<NGROUP * NBATCH, 256, 0, stream>>>(A16, E, Sg);
  top_scan<<<NBATCH, 256, 0, stream>>>(A256, Sg, h0, G);
  carry_scan2<<<NGROUP * NBATCH, 256, 0, stream>>>(A16, E, G, Hc);

  // final scan, h overwrites U
  mfma_scan<<<NCHUNK, 512, 0, stream>>>(fA_hi, fA_lo, Hc, U, E, 1);

  // y = h @ C
  mfma_gemm<<<2048, 512, 0, stream>>>(U, fC_hi, fC_lo, y, 1);
}

// Round 4
// 394.239 us; speedup vs baseline: 2.7731x; 1.1027x over previous
//
#include <hip/hip_runtime.h>

// Linear RNN scan: h_t = h_{t-1}@A + x_t@B ; y_t = h_t@C
// B=8, S=4096, IN=STATE=OUT=256.
// MFMA 16x16x32 f16, 2-term split (hi + 2048*lo), f32 accumulate.
// Chunked scan: 512 chunks x 8 steps; groups of 16 chunks (32 groups).
//   mfma_gemm   : U = x@B   (M=64/block, 16 waves, resident B-frags)
//   gemm256 x7  : A^2..A^128 (f32)
//   mfma_scan 0 : 2 chunks/block (M=16, no pad waste), chunk-end states E
//   carry_collect(A^8) / top_scan(A^128) / carry_scan2(A^8): entry states Hc
//   mfma_scan 1 : final scan from Hc, h overwrites U
//   mfma_gemm   : y = h@C

#define SEQ    4096
#define NBATCH 8
#define ND     256
#define CHUNK  8
#define NCHUNK 512
#define GSZ    16
#define NGRP   32
#define LOSC   2048.0f
#define LOINV  (1.0f/2048.0f)

typedef _Float16 fp16_t;
typedef __attribute__((ext_vector_type(8))) _Float16 f16x8;
typedef __attribute__((ext_vector_type(4))) _Float16 f16x4;
typedef __attribute__((ext_vector_type(4))) float f32x4;

// ---------- pack A,B,C into B-operand frag arrays (hi/lo f16) ----------
// frag linear index: ((tile*8 + slice)*64 + lane)*8 + j
// value = M[k][n], k = slice*32 + (lane>>4)*8 + j, n = tile*16 + (lane&15)
__global__ __launch_bounds__(64) void prep_frags3(
    const float* __restrict__ A, const float* __restrict__ B,
    const float* __restrict__ C,
    fp16_t* __restrict__ fAh, fp16_t* __restrict__ fAl,
    fp16_t* __restrict__ fBh, fp16_t* __restrict__ fBl,
    fp16_t* __restrict__ fCh, fp16_t* __restrict__ fCl) {
  const int which = blockIdx.x >> 7;
  const int blk   = blockIdx.x & 127;
  const float* M = (which == 0) ? A : (which == 1) ? B : C;
  fp16_t* hi = (which == 0) ? fAh : (which == 1) ? fBh : fCh;
  fp16_t* lo = (which == 0) ? fAl : (which == 1) ? fBl : fCl;
  const int lane = threadIdx.x;
  const int tile = blk >> 3, slice = blk & 7;
  const int n  = tile * 16 + (lane & 15);
  const int k0 = slice * 32 + (lane >> 4) * 8;
  f16x8 vh, vl;
  #pragma unroll
  for (int j = 0; j < 8; ++j) {
    const float v = M[(size_t)(k0 + j) * ND + n];
    const fp16_t h = (fp16_t)v;
    vh[j] = h;
    vl[j] = (fp16_t)((v - (float)h) * LOSC);
  }
  const size_t fo = ((size_t)blk * 64 + lane) * 8;
  *(f16x8*)&hi[fo] = vh;
  *(f16x8*)&lo[fo] = vl;
}

// ---------- MFMA GEMM: Out[m][:] = X[m][:] @ M,  m = s*8+b, M-block = 64 ----------
// mode 0 (xb): X rows remapped from x[b][s][:];  mode 1 (y): Out remapped to y[b][s][:]
__global__ __launch_bounds__(1024, 4) void mfma_gemm(const float* __restrict__ X,
                                                     const fp16_t* __restrict__ Mhi,
                                                     const fp16_t* __restrict__ Mlo,
                                                     float* __restrict__ Out,
                                                     int mode) {
  const int m0   = blockIdx.x * 64;
  const int tid  = threadIdx.x;
  const int lane = tid & 63;
  const int w    = tid >> 6;          // 16 waves, N-tile w
  const int arow = lane & 15;
  const int akg  = lane >> 4;
  const int crow0 = akg * 4;
  const int ccol  = arow;

  __shared__ fp16_t Xh[64 * ND];      // hi, XOR-swizzled rows
  __shared__ fp16_t Xl[64 * ND];
  char* Xhb = (char*)Xh;
  char* Xlb = (char*)Xl;

  // stage 64 rows of X, converted to hi/lo (once per block)
  {
    const int r0   = tid >> 6;        // 0..15
    const int col0 = (tid & 63) * 4;  // 0..252
    #pragma unroll
    for (int rr = 0; rr < 4; ++rr) {
      const int row = rr * 16 + r0;
      const int m = m0 + row;
      const size_t in_row = (mode == 0)
          ? ((size_t)(m & 7) * SEQ + (m >> 3))
          : (size_t)m;
      const float4 xv = *(const float4*)&X[in_row * ND + col0];
      const float a[4] = {xv.x, xv.y, xv.z, xv.w};
      f16x4 vh, vl;
      #pragma unroll
      for (int j = 0; j < 4; ++j) {
        const fp16_t h = (fp16_t)a[j];
        vh[j] = h;
        vl[j] = (fp16_t)((a[j] - (float)h) * LOSC);
      }
      const int byte = (row * 512 + col0 * 2) ^ ((row & 7) << 4);
      *(f16x4*)(Xhb + byte) = vh;
      *(f16x4*)(Xlb + byte) = vl;
    }
  }

  // resident B-frags for this wave's N-tile
  f16x8 BH[8], BL[8];
  #pragma unroll
  for (int s = 0; s < 8; ++s) {
    const size_t fo = (((size_t)w * 8 + s) * 64 + lane) * 8;
    BH[s] = *(const f16x8*)&Mhi[fo];
    BL[s] = *(const f16x8*)&Mlo[fo];
  }
  __syncthreads();

  f32x4 accm[4], accl[4];
  #pragma unroll
  for (int mt = 0; mt < 4; ++mt) {
    accm[mt] = (f32x4)0.0f;
    accl[mt] = (f32x4)0.0f;
  }

  #pragma unroll
  for (int s = 0; s < 8; ++s) {
    #pragma unroll
    for (int mt = 0; mt < 4; ++mt) {
      const int row = mt * 16 + arow;
      const int byte = (row * 512 + s * 64 + akg * 16) ^ ((row & 7) << 4);
      const f16x8 ah = *(const f16x8*)(Xhb + byte);
      const f16x8 al = *(const f16x8*)(Xlb + byte);
      accm[mt] = __builtin_amdgcn_mfma_f32_16x16x32_f16(ah, BH[s], accm[mt], 0, 0, 0);
      accl[mt] = __builtin_amdgcn_mfma_f32_16x16x32_f16(ah, BL[s], accl[mt], 0, 0, 0);
      accl[mt] = __builtin_amdgcn_mfma_f32_16x16x32_f16(al, BH[s], accl[mt], 0, 0, 0);
    }
  }

  #pragma unroll
  for (int mt = 0; mt < 4; ++mt) {
    #pragma unroll
    for (int r = 0; r < 4; ++r) {
      const int row = mt * 16 + crow0 + r;
      const int m = m0 + row;
      const size_t out_row = (mode == 1)
          ? ((size_t)(m & 7) * SEQ + (m >> 3))
          : (size_t)m;
      Out[out_row * ND + w * 16 + ccol] = accm[mt][r] + accl[mt][r] * LOINV;
    }
  }
}

// ---------- MFMA chunk scan: 2 chunks per block (M = 2x8 = 16 rows) ----------
// mode 0: h starts 0, store only chunk-end E ; mode 1: h starts Hc, h overwrites U
__global__ __launch_bounds__(1024, 4) void mfma_scan(const fp16_t* __restrict__ Ahi,
                                                     const fp16_t* __restrict__ Alo,
                                                     const float* __restrict__ Hc,
                                                     float* __restrict__ U,
                                                     float* __restrict__ E,
                                                     int mode) {
  const int c2   = blockIdx.x;        // chunks 2*c2, 2*c2+1
  const int tid  = threadIdx.x;
  const int lane = tid & 63;
  const int w    = tid >> 6;          // 16 waves, N-tile w
  const int arow = lane & 15;
  const int akg  = lane >> 4;
  const int crow0 = akg * 4;
  const int ccol  = arow;

  __shared__ fp16_t hH[16 * ND];
  __shared__ fp16_t hL[16 * ND];
  char* hHb = (char*)hH;
  char* hLb = (char*)hL;

  // init h rows (Hc or zero)
  {
    const int row  = tid >> 6;
    const int col0 = (tid & 63) * 4;
    const int c = 2 * c2 + (row >> 3);
    const int b = row & 7;
    float4 v = make_float4(0.f, 0.f, 0.f, 0.f);
    if (mode == 1) v = *(const float4*)&Hc[((size_t)c * NBATCH + b) * ND + col0];
    const float a[4] = {v.x, v.y, v.z, v.w};
    f16x4 vh, vl;
    #pragma unroll
    for (int j = 0; j < 4; ++j) {
      const fp16_t h = (fp16_t)a[j];
      vh[j] = h;
      vl[j] = (fp16_t)((a[j] - (float)h) * LOSC);
    }
    const int byte = (row * 512 + col0 * 2) ^ ((row & 7) << 4);
    *(f16x4*)(hHb + byte) = vh;
    *(f16x4*)(hLb + byte) = vl;
  }

  // resident A-frags (B-operand) for this wave's N-tile
  f16x8 BH[8], BL[8];
  #pragma unroll
  for (int s = 0; s < 8; ++s) {
    const size_t fo = (((size_t)w * 8 + s) * 64 + lane) * 8;
    BH[s] = *(const f16x8*)&Ahi[fo];
    BL[s] = *(const f16x8*)&Alo[fo];
  }
  __syncthreads();

  // this lane's 4 C-rows: chunk cc, batches bb..bb+3, column col
  const int cc  = 2 * c2 + (crow0 >> 3);
  const int bb  = crow0 & 7;
  const int col = w * 16 + ccol;

  float uv[4], uvn[4];
  #pragma unroll
  for (int r = 0; r < 4; ++r)
    uv[r] = U[((size_t)(cc * CHUNK) * NBATCH + bb + r) * ND + col];

  f32x4 res;
  for (int j = 0; j < CHUNK; ++j) {
    if (j + 1 < CHUNK) {              // prefetch next step's u
      #pragma unroll
      for (int r = 0; r < 4; ++r)
        uvn[r] = U[((size_t)(cc * CHUNK + j + 1) * NBATCH + bb + r) * ND + col];
    }
    f32x4 accm, accl;
    #pragma unroll
    for (int r = 0; r < 4; ++r) accm[r] = uv[r];
    accl = (f32x4)0.0f;
    #pragma unroll
    for (int s = 0; s < 8; ++s) {
      const int byte = (arow * 512 + s * 64 + akg * 16) ^ ((arow & 7) << 4);
      const f16x8 ah = *(const f16x8*)(hHb + byte);
      const f16x8 al = *(const f16x8*)(hLb + byte);
      accm = __builtin_amdgcn_mfma_f32_16x16x32_f16(ah, BH[s], accm, 0, 0, 0);
      accl = __builtin_amdgcn_mfma_f32_16x16x32_f16(ah, BL[s], accl, 0, 0, 0);
      accl = __builtin_amdgcn_mfma_f32_16x16x32_f16(al, BH[s], accl, 0, 0, 0);
    }
    #pragma unroll
    for (int r = 0; r < 4; ++r) res[r] = accm[r] + accl[r] * LOINV;
    __syncthreads();                  // reads of old h done
    #pragma unroll
    for (int r = 0; r < 4; ++r) {
      const int row = crow0 + r;
      const int byte = (row * 512 + col * 2) ^ ((row & 7) << 4);
      const float v = res[r];
      const fp16_t vh = (fp16_t)v;
      *(fp16_t*)(hHb + byte) = vh;
      *(fp16_t*)(hLb + byte) = (fp16_t)((v - (float)vh) * LOSC);
      if (mode == 1)
        U[((size_t)(cc * CHUNK + j) * NBATCH + bb + r) * ND + col] = v;
    }
    #pragma unroll
    for (int r = 0; r < 4; ++r) uv[r] = uvn[r];
    __syncthreads();                  // new h visible
  }

  if (mode == 0) {
    #pragma unroll
    for (int r = 0; r < 4; ++r)
      E[((size_t)cc * NBATCH + bb + r) * ND + col] = res[r];
  }
}

// ---------- dense 256x256 f32 GEMM (A-power chain) ----------
__global__ __launch_bounds__(256) void gemm256(const float* __restrict__ X,
                                               const float* __restrict__ Y,
                                               float* __restrict__ Out) {
  const int m0 = blockIdx.x * 4;
  const int n  = threadIdx.x;
  __shared__ float Xs[ND][4];
  #pragma unroll
  for (int r = 0; r < 4; ++r) Xs[n][r] = X[(m0 + r) * ND + n];
  __syncthreads();
  float a0 = 0.f, a1 = 0.f, a2 = 0.f, a3 = 0.f;
  #pragma unroll 8
  for (int k = 0; k < ND; ++k) {
    const float yv = Y[k * ND + n];
    const float4 xv = *(const float4*)&Xs[k][0];
    a0 = fmaf(xv.x, yv, a0);
    a1 = fmaf(xv.y, yv, a1);
    a2 = fmaf(xv.z, yv, a2);
    a3 = fmaf(xv.w, yv, a3);
  }
  Out[(m0 + 0) * ND + n] = a0;
  Out[(m0 + 1) * ND + n] = a1;
  Out[(m0 + 2) * ND + n] = a2;
  Out[(m0 + 3) * ND + n] = a3;
}

// ---------- per-group scan of E with A8; final S[g] only ----------
__global__ __launch_bounds__(256) void carry_collect(const float* __restrict__ A8,
                                                     const float* __restrict__ E,
                                                     float* __restrict__ S) {
  const int g = blockIdx.x >> 3;
  const int b = blockIdx.x & 7;
  const int n = threadIdx.x;
  __shared__ float H[ND];
  H[n] = 0.f;
  __syncthreads();
  float acc = 0.f;
  for (int j = 0; j < GSZ; ++j) {
    const int c = g * GSZ + j;
    acc = E[((size_t)c * NBATCH + b) * ND + n];
    #pragma unroll 4
    for (int k = 0; k < ND; k += 4) {
      const float4 hk = *(const float4*)&H[k];
      acc = fmaf(hk.x, A8[(k + 0) * ND + n], acc);
      acc = fmaf(hk.y, A8[(k + 1) * ND + n], acc);
      acc = fmaf(hk.z, A8[(k + 2) * ND + n], acc);
      acc = fmaf(hk.w, A8[(k + 3) * ND + n], acc);
    }
    __syncthreads();
    H[n] = acc;
    __syncthreads();
  }
  S[((size_t)g * NBATCH + b) * ND + n] = acc;
}

// ---------- top scan over 32 groups with A128 ----------
__global__ __launch_bounds__(256) void top_scan(const float* __restrict__ A128,
                                                const float* __restrict__ S,
                                                const float* __restrict__ h0,
                                                float* __restrict__ G) {
  const int b = blockIdx.x;
  const int n = threadIdx.x;
  __shared__ float H[ND];
  float hv = h0[n];
  H[n] = hv;
  G[(size_t)b * ND + n] = hv;
  __syncthreads();
  for (int g = 0; g < NGRP - 1; ++g) {
    float acc = S[((size_t)g * NBATCH + b) * ND + n];
    #pragma unroll 4
    for (int k = 0; k < ND; k += 4) {
      const float4 hk = *(const float4*)&H[k];
      acc = fmaf(hk.x, A128[(k + 0) * ND + n], acc);
      acc = fmaf(hk.y, A128[(k + 1) * ND + n], acc);
      acc = fmaf(hk.z, A128[(k + 2) * ND + n], acc);
      acc = fmaf(hk.w, A128[(k + 3) * ND + n], acc);
    }
    __syncthreads();
    H[n] = acc;
    G[((size_t)(g + 1) * NBATCH + b) * ND + n] = acc;
    __syncthreads();
  }
}

// ---------- materialize all chunk-entry states ----------
__global__ __launch_bounds__(256) void carry_scan2(const float* __restrict__ A8,
                                                   const float* __restrict__ E,
                                                   const float* __restrict__ G,
                                                   float* __restrict__ Hc) {
  const int g = blockIdx.x >> 3;
  const int b = blockIdx.x & 7;
  const int n = threadIdx.x;
  __shared__ float H[ND];
  float acc = G[((size_t)g * NBATCH + b) * ND + n];
  H[n] = acc;
  Hc[((size_t)(g * GSZ) * NBATCH + b) * ND + n] = acc;
  __syncthreads();
  for (int j = 0; j < GSZ - 1; ++j) {
    const int c = g * GSZ + j;
    acc = E[((size_t)c * NBATCH + b) * ND + n];
    #pragma unroll 4
    for (int k = 0; k < ND; k += 4) {
      const float4 hk = *(const float4*)&H[k];
      acc = fmaf(hk.x, A8[(k + 0) * ND + n], acc);
      acc = fmaf(hk.y, A8[(k + 1) * ND + n], acc);
      acc = fmaf(hk.z, A8[(k + 2) * ND + n], acc);
      acc = fmaf(hk.w, A8[(k + 3) * ND + n], acc);
    }
    __syncthreads();
    H[n] = acc;
    Hc[((size_t)(c + 1) * NBATCH + b) * ND + n] = acc;
    __syncthreads();
  }
}

extern "C" void kernel_launch(void* const* d_in, const int* in_sizes, int n_in,
                              void* d_out, int out_size, void* d_ws, size_t ws_size,
                              hipStream_t stream) {
  const float* x  = (const float*)d_in[0];
  const float* A  = (const float*)d_in[1];
  const float* Bm = (const float*)d_in[2];
  const float* Cm = (const float*)d_in[3];
  const float* h0 = (const float*)d_in[4];
  float* y = (float*)d_out;

  float* U    = (float*)d_ws;                        // 8,388,608
  float* t0   = U + (size_t)SEQ * NBATCH * ND;       // 65,536
  float* t1   = t0 + ND * ND;
  float* A8   = t1 + ND * ND;
  float* A128 = A8 + ND * ND;
  float* E    = A128 + ND * ND;                      // 1,048,576
  float* Sg   = E + (size_t)NCHUNK * NBATCH * ND;    // 65,536
  float* G    = Sg + (size_t)NGRP * NBATCH * ND;     // 65,536
  float* Hc   = G + (size_t)NGRP * NBATCH * ND;      // 1,048,576
  fp16_t* fA_hi = (fp16_t*)(Hc + (size_t)NCHUNK * NBATCH * ND);
  fp16_t* fA_lo = fA_hi + ND * ND;
  fp16_t* fB_hi = fA_lo + ND * ND;
  fp16_t* fB_lo = fB_hi + ND * ND;
  fp16_t* fC_hi = fB_lo + ND * ND;
  fp16_t* fC_lo = fC_hi + ND * ND;

  // pack matrices into fragment arrays (one launch)
  prep_frags3<<<384, 64, 0, stream>>>(A, Bm, Cm, fA_hi, fA_lo, fB_hi, fB_lo,
                                      fC_hi, fC_lo);

  // U = x @ B
  mfma_gemm<<<512, 1024, 0, stream>>>(x, fB_hi, fB_lo, U, 0);

  // A powers (f32): A^8, A^128
  gemm256<<<64, 256, 0, stream>>>(A,  A,  t0);       // A^2
  gemm256<<<64, 256, 0, stream>>>(t0, t0, t1);       // A^4
  gemm256<<<64, 256, 0, stream>>>(t1, t1, A8);       // A^8
  gemm256<<<64, 256, 0, stream>>>(A8, A8, t0);       // A^16
  gemm256<<<64, 256, 0, stream>>>(t0, t0, t1);       // A^32
  gemm256<<<64, 256, 0, stream>>>(t1, t1, t0);       // A^64
  gemm256<<<64, 256, 0, stream>>>(t0, t0, A128);     // A^128

  // chunk local ends
  mfma_scan<<<NCHUNK / 2, 1024, 0, stream>>>(fA_hi, fA_lo, Hc, U, E, 0);

  // carry hierarchy (f32)
  carry_collect<<<NGRP * NBATCH, 256, 0, stream>>>(A8, E, Sg);
  top_scan<<<NBATCH, 256, 0, stream>>>(A128, Sg, h0, G);
  carry_scan2<<<NGRP * NBATCH, 256, 0, stream>>>(A8, E, G, Hc);

  // final scan, h overwrites U
  mfma_scan<<<NCHUNK / 2, 1024, 0, stream>>>(fA_hi, fA_lo, Hc, U, E, 1);

  // y = h @ C
  mfma_gemm<<<512, 1024, 0, stream>>>(U, fC_hi, fC_lo, y, 1);
}

// Round 5
// 270.418 us; speedup vs baseline: 4.0429x; 1.4579x over previous
//
#include <hip/hip_runtime.h>

// Linear RNN scan: h_t = h_{t-1}@A + x_t@B ; y_t = h_t@C
// B=8, S=4096, IN=STATE=OUT=256.
// MFMA 16x16x32 f16, 2-term split (hi + 2048*lo), f32 accumulate.
// Scan hierarchy (all levels run on the unified MFMA recurrence kernel):
//   chunk level : 512 chunks x 8 steps   (multiplier A)
//   group level : 32 groups x 16 chunks  (multiplier A^8)
//   top level   : 31 steps over groups   (multiplier A^128)

#define SEQ    4096
#define NBATCH 8
#define ND     256
#define CHUNK  8
#define NCHUNK 512
#define GSZ    16
#define NGRP   32
#define LOSC   2048.0f
#define LOINV  (1.0f/2048.0f)

typedef _Float16 fp16_t;
typedef __attribute__((ext_vector_type(8))) _Float16 f16x8;
typedef __attribute__((ext_vector_type(4))) _Float16 f16x4;
typedef __attribute__((ext_vector_type(4))) float f32x4;

// ---------- pack A,B,C into B-operand frag arrays (hi/lo f16) ----------
// frag linear index: ((tile*8 + slice)*64 + lane)*8 + j
// value = M[k][n], k = slice*32 + (lane>>4)*8 + j, n = tile*16 + (lane&15)
__global__ __launch_bounds__(64) void prep_frags3(
    const float* __restrict__ A, const float* __restrict__ B,
    const float* __restrict__ C,
    fp16_t* __restrict__ fAh, fp16_t* __restrict__ fAl,
    fp16_t* __restrict__ fBh, fp16_t* __restrict__ fBl,
    fp16_t* __restrict__ fCh, fp16_t* __restrict__ fCl) {
  const int which = blockIdx.x >> 7;
  const int blk   = blockIdx.x & 127;
  const float* M = (which == 0) ? A : (which == 1) ? B : C;
  fp16_t* hi = (which == 0) ? fAh : (which == 1) ? fBh : fCh;
  fp16_t* lo = (which == 0) ? fAl : (which == 1) ? fBl : fCl;
  const int lane = threadIdx.x;
  const int tile = blk >> 3, slice = blk & 7;
  const int n  = tile * 16 + (lane & 15);
  const int k0 = slice * 32 + (lane >> 4) * 8;
  f16x8 vh, vl;
  #pragma unroll
  for (int j = 0; j < 8; ++j) {
    const float v = M[(size_t)(k0 + j) * ND + n];
    const fp16_t h = (fp16_t)v;
    vh[j] = h;
    vl[j] = (fp16_t)((v - (float)h) * LOSC);
  }
  const size_t fo = ((size_t)blk * 64 + lane) * 8;
  *(f16x8*)&hi[fo] = vh;
  *(f16x8*)&lo[fo] = vl;
}

// ---------- pack A8, A128 into frag arrays ----------
__global__ __launch_bounds__(64) void prep_frags2(
    const float* __restrict__ M0, const float* __restrict__ M1,
    fp16_t* __restrict__ h0p, fp16_t* __restrict__ l0p,
    fp16_t* __restrict__ h1p, fp16_t* __restrict__ l1p) {
  const int which = blockIdx.x >> 7;
  const int blk   = blockIdx.x & 127;
  const float* M = (which == 0) ? M0 : M1;
  fp16_t* hi = (which == 0) ? h0p : h1p;
  fp16_t* lo = (which == 0) ? l0p : l1p;
  const int lane = threadIdx.x;
  const int tile = blk >> 3, slice = blk & 7;
  const int n  = tile * 16 + (lane & 15);
  const int k0 = slice * 32 + (lane >> 4) * 8;
  f16x8 vh, vl;
  #pragma unroll
  for (int j = 0; j < 8; ++j) {
    const float v = M[(size_t)(k0 + j) * ND + n];
    const fp16_t h = (fp16_t)v;
    vh[j] = h;
    vl[j] = (fp16_t)((v - (float)h) * LOSC);
  }
  const size_t fo = ((size_t)blk * 64 + lane) * 8;
  *(f16x8*)&hi[fo] = vh;
  *(f16x8*)&lo[fo] = vl;
}

// ---------- MFMA GEMM: Out[m][:] = X[m][:] @ M,  m = s*8+b, M-block = 64 ----------
// mode 0 (xb): X rows remapped from x[b][s][:];  mode 1 (y): Out remapped to y[b][s][:]
__global__ __launch_bounds__(1024, 4) void mfma_gemm(const float* __restrict__ X,
                                                     const fp16_t* __restrict__ Mhi,
                                                     const fp16_t* __restrict__ Mlo,
                                                     float* __restrict__ Out,
                                                     int mode) {
  const int m0   = blockIdx.x * 64;
  const int tid  = threadIdx.x;
  const int lane = tid & 63;
  const int w    = tid >> 6;          // 16 waves, N-tile w
  const int arow = lane & 15;
  const int akg  = lane >> 4;
  const int crow0 = akg * 4;
  const int ccol  = arow;

  __shared__ fp16_t Xh[64 * ND];      // hi, XOR-swizzled rows
  __shared__ fp16_t Xl[64 * ND];
  char* Xhb = (char*)Xh;
  char* Xlb = (char*)Xl;

  // stage 64 rows of X, converted to hi/lo (once per block)
  {
    const int r0   = tid >> 6;        // 0..15
    const int col0 = (tid & 63) * 4;  // 0..252
    #pragma unroll
    for (int rr = 0; rr < 4; ++rr) {
      const int row = rr * 16 + r0;
      const int m = m0 + row;
      const size_t in_row = (mode == 0)
          ? ((size_t)(m & 7) * SEQ + (m >> 3))
          : (size_t)m;
      const float4 xv = *(const float4*)&X[in_row * ND + col0];
      const float a[4] = {xv.x, xv.y, xv.z, xv.w};
      f16x4 vh, vl;
      #pragma unroll
      for (int j = 0; j < 4; ++j) {
        const fp16_t h = (fp16_t)a[j];
        vh[j] = h;
        vl[j] = (fp16_t)((a[j] - (float)h) * LOSC);
      }
      const int byte = (row * 512 + col0 * 2) ^ ((row & 7) << 4);
      *(f16x4*)(Xhb + byte) = vh;
      *(f16x4*)(Xlb + byte) = vl;
    }
  }

  // resident B-frags for this wave's N-tile
  f16x8 BH[8], BL[8];
  #pragma unroll
  for (int s = 0; s < 8; ++s) {
    const size_t fo = (((size_t)w * 8 + s) * 64 + lane) * 8;
    BH[s] = *(const f16x8*)&Mhi[fo];
    BL[s] = *(const f16x8*)&Mlo[fo];
  }
  __syncthreads();

  f32x4 accm[4], accl[4];
  #pragma unroll
  for (int mt = 0; mt < 4; ++mt) {
    accm[mt] = (f32x4)0.0f;
    accl[mt] = (f32x4)0.0f;
  }

  #pragma unroll
  for (int s = 0; s < 8; ++s) {
    #pragma unroll
    for (int mt = 0; mt < 4; ++mt) {
      const int row = mt * 16 + arow;
      const int byte = (row * 512 + s * 64 + akg * 16) ^ ((row & 7) << 4);
      const f16x8 ah = *(const f16x8*)(Xhb + byte);
      const f16x8 al = *(const f16x8*)(Xlb + byte);
      accm[mt] = __builtin_amdgcn_mfma_f32_16x16x32_f16(ah, BH[s], accm[mt], 0, 0, 0);
      accl[mt] = __builtin_amdgcn_mfma_f32_16x16x32_f16(ah, BL[s], accl[mt], 0, 0, 0);
      accl[mt] = __builtin_amdgcn_mfma_f32_16x16x32_f16(al, BH[s], accl[mt], 0, 0, 0);
    }
  }

  #pragma unroll
  for (int mt = 0; mt < 4; ++mt) {
    #pragma unroll
    for (int r = 0; r < 4; ++r) {
      const int row = mt * 16 + crow0 + r;
      const int m = m0 + row;
      const size_t out_row = (mode == 1)
          ? ((size_t)(m & 7) * SEQ + (m >> 3))
          : (size_t)m;
      Out[out_row * ND + w * 16 + ccol] = accm[mt][r] + accl[mt][r] * LOINV;
    }
  }
}

// ---------- unified MFMA recurrence kernel ----------
// Each block runs TWO independent 8-row sequences (seq = blockIdx.x*2 + rowgrp).
// For nupd steps: h = h @ Mult + In[(seq*gstride + j)*NB + b].
// Init: null -> zero; init_bcast -> Init[col] (shared); else Init[(seq*NB+b)*ND+col].
// entry_mode=0: OutEach (if set) written at read position (state after step j).
// entry_mode=1: OutEach gets Init at position (seq*gstride), state after step j at
//               position (seq*gstride + j + 1).
// OutFinal (if set): final state at row (seq*NB+b).
__global__ __launch_bounds__(1024, 4) void mfma_rscan(
    const fp16_t* __restrict__ Mh, const fp16_t* __restrict__ Ml,
    const float* __restrict__ Init,
    const float* In,
    float* OutEach,
    float* __restrict__ OutFinal,
    int nupd, int gstride, int nseq, int init_bcast, int entry_mode) {
  const int seq0 = blockIdx.x * 2;
  const int tid  = threadIdx.x;
  const int lane = tid & 63;
  const int w    = tid >> 6;
  const int arow = lane & 15;
  const int akg  = lane >> 4;
  const int crow0 = akg * 4;
  const int ccol  = arow;

  __shared__ fp16_t hH[16 * ND];
  __shared__ fp16_t hL[16 * ND];
  char* hHb = (char*)hH;
  char* hLb = (char*)hL;

  // init h rows
  {
    const int row  = tid >> 6;          // 0..15
    const int col0 = (tid & 63) * 4;
    const int sq = seq0 + (row >> 3);
    const int b  = row & 7;
    float4 v = make_float4(0.f, 0.f, 0.f, 0.f);
    if (Init != nullptr && sq < nseq) {
      const size_t off = init_bcast ? (size_t)col0
                                    : ((size_t)sq * NBATCH + b) * ND + col0;
      v = *(const float4*)&Init[off];
      if (entry_mode && OutEach != nullptr)
        *(float4*)&OutEach[((size_t)sq * gstride * NBATCH + b) * ND + col0] = v;
    }
    const float a[4] = {v.x, v.y, v.z, v.w};
    f16x4 vh, vl;
    #pragma unroll
    for (int j = 0; j < 4; ++j) {
      const fp16_t h = (fp16_t)a[j];
      vh[j] = h;
      vl[j] = (fp16_t)((a[j] - (float)h) * LOSC);
    }
    const int byte = (row * 512 + col0 * 2) ^ ((row & 7) << 4);
    *(f16x4*)(hHb + byte) = vh;
    *(f16x4*)(hLb + byte) = vl;
  }

  // resident multiplier frags (B-operand) for this wave's N-tile
  f16x8 BH[8], BL[8];
  #pragma unroll
  for (int s = 0; s < 8; ++s) {
    const size_t fo = (((size_t)w * 8 + s) * 64 + lane) * 8;
    BH[s] = *(const f16x8*)&Mh[fo];
    BL[s] = *(const f16x8*)&Ml[fo];
  }
  __syncthreads();

  // this lane's 4 C-rows
  int sqr[4], brr[4];
  #pragma unroll
  for (int r = 0; r < 4; ++r) {
    const int row = crow0 + r;
    sqr[r] = seq0 + (row >> 3);
    brr[r] = row & 7;
  }
  const int col = w * 16 + ccol;

  float uv[4], uvn[4];
  #pragma unroll
  for (int r = 0; r < 4; ++r)
    uv[r] = In[((size_t)(sqr[r] * gstride) * NBATCH + brr[r]) * ND + col];

  f32x4 res;
  for (int j = 0; j < nupd; ++j) {
    if (j + 1 < nupd) {
      #pragma unroll
      for (int r = 0; r < 4; ++r)
        uvn[r] = In[((size_t)(sqr[r] * gstride + j + 1) * NBATCH + brr[r]) * ND + col];
    }
    f32x4 accm, accl;
    #pragma unroll
    for (int r = 0; r < 4; ++r) accm[r] = uv[r];
    accl = (f32x4)0.0f;
    #pragma unroll
    for (int s = 0; s < 8; ++s) {
      const int byte = (arow * 512 + s * 64 + akg * 16) ^ ((arow & 7) << 4);
      const f16x8 ah = *(const f16x8*)(hHb + byte);
      const f16x8 al = *(const f16x8*)(hLb + byte);
      accm = __builtin_amdgcn_mfma_f32_16x16x32_f16(ah, BH[s], accm, 0, 0, 0);
      accl = __builtin_amdgcn_mfma_f32_16x16x32_f16(ah, BL[s], accl, 0, 0, 0);
      accl = __builtin_amdgcn_mfma_f32_16x16x32_f16(al, BH[s], accl, 0, 0, 0);
    }
    #pragma unroll
    for (int r = 0; r < 4; ++r) res[r] = accm[r] + accl[r] * LOINV;
    __syncthreads();                  // reads of old h done
    #pragma unroll
    for (int r = 0; r < 4; ++r) {
      const int row = crow0 + r;
      const int byte = (row * 512 + col * 2) ^ ((row & 7) << 4);
      const float v = res[r];
      const fp16_t vh = (fp16_t)v;
      *(fp16_t*)(hHb + byte) = vh;
      *(fp16_t*)(hLb + byte) = (fp16_t)((v - (float)vh) * LOSC);
      if (OutEach != nullptr && sqr[r] < nseq) {
        const size_t pos = entry_mode
            ? ((size_t)(sqr[r] * gstride + j + 1) * NBATCH + brr[r]) * ND + col
            : ((size_t)(sqr[r] * gstride + j) * NBATCH + brr[r]) * ND + col;
        OutEach[pos] = v;
      }
    }
    #pragma unroll
    for (int r = 0; r < 4; ++r) uv[r] = uvn[r];
    __syncthreads();                  // new h visible
  }

  if (OutFinal != nullptr) {
    #pragma unroll
    for (int r = 0; r < 4; ++r)
      if (sqr[r] < nseq)
        OutFinal[((size_t)sqr[r] * NBATCH + brr[r]) * ND + col] = res[r];
  }
}

// ---------- dense 256x256 f32 GEMM (A-power chain) ----------
__global__ __launch_bounds__(256) void gemm256(const float* __restrict__ X,
                                               const float* __restrict__ Y,
                                               float* __restrict__ Out) {
  const int m0 = blockIdx.x * 4;
  const int n  = threadIdx.x;
  __shared__ float Xs[ND][4];
  #pragma unroll
  for (int r = 0; r < 4; ++r) Xs[n][r] = X[(m0 + r) * ND + n];
  __syncthreads();
  float a0 = 0.f, a1 = 0.f, a2 = 0.f, a3 = 0.f;
  #pragma unroll 8
  for (int k = 0; k < ND; ++k) {
    const float yv = Y[k * ND + n];
    const float4 xv = *(const float4*)&Xs[k][0];
    a0 = fmaf(xv.x, yv, a0);
    a1 = fmaf(xv.y, yv, a1);
    a2 = fmaf(xv.z, yv, a2);
    a3 = fmaf(xv.w, yv, a3);
  }
  Out[(m0 + 0) * ND + n] = a0;
  Out[(m0 + 1) * ND + n] = a1;
  Out[(m0 + 2) * ND + n] = a2;
  Out[(m0 + 3) * ND + n] = a3;
}

extern "C" void kernel_launch(void* const* d_in, const int* in_sizes, int n_in,
                              void* d_out, int out_size, void* d_ws, size_t ws_size,
                              hipStream_t stream) {
  const float* x  = (const float*)d_in[0];
  const float* A  = (const float*)d_in[1];
  const float* Bm = (const float*)d_in[2];
  const float* Cm = (const float*)d_in[3];
  const float* h0 = (const float*)d_in[4];
  float* y = (float*)d_out;

  float* U    = (float*)d_ws;                        // 8,388,608
  float* t0   = U + (size_t)SEQ * NBATCH * ND;       // 65,536 (reused for A8 frags)
  float* t1   = t0 + ND * ND;                        // 65,536 (reused for A128 frags)
  float* A8   = t1 + ND * ND;
  float* A128 = A8 + ND * ND;
  float* E    = A128 + ND * ND;                      // 1,048,576
  float* Sg   = E + (size_t)NCHUNK * NBATCH * ND;    // 65,536
  float* G    = Sg + (size_t)NGRP * NBATCH * ND;     // 65,536
  float* Hc   = G + (size_t)NGRP * NBATCH * ND;      // 1,048,576
  fp16_t* fA_hi = (fp16_t*)(Hc + (size_t)NCHUNK * NBATCH * ND);
  fp16_t* fA_lo = fA_hi + ND * ND;
  fp16_t* fB_hi = fA_lo + ND * ND;
  fp16_t* fB_lo = fB_hi + ND * ND;
  fp16_t* fC_hi = fB_lo + ND * ND;
  fp16_t* fC_lo = fC_hi + ND * ND;
  // frag arrays for A8 / A128 overlaid on dead t0/t1 scratch
  fp16_t* fA8_hi   = (fp16_t*)t0;
  fp16_t* fA8_lo   = fA8_hi + ND * ND;
  fp16_t* fA128_hi = (fp16_t*)t1;
  fp16_t* fA128_lo = fA128_hi + ND * ND;

  // pack A,B,C into fragment arrays
  prep_frags3<<<384, 64, 0, stream>>>(A, Bm, Cm, fA_hi, fA_lo, fB_hi, fB_lo,
                                      fC_hi, fC_lo);

  // A powers (f32): A^8, A^128  (t0/t1 scratch, then freed)
  gemm256<<<64, 256, 0, stream>>>(A,  A,  t0);       // A^2
  gemm256<<<64, 256, 0, stream>>>(t0, t0, t1);       // A^4
  gemm256<<<64, 256, 0, stream>>>(t1, t1, A8);       // A^8
  gemm256<<<64, 256, 0, stream>>>(A8, A8, t0);       // A^16
  gemm256<<<64, 256, 0, stream>>>(t0, t0, t1);       // A^32
  gemm256<<<64, 256, 0, stream>>>(t1, t1, t0);       // A^64
  gemm256<<<64, 256, 0, stream>>>(t0, t0, A128);     // A^128

  // pack A8/A128 into frags (t0/t1 now reusable as the frag storage)
  prep_frags2<<<256, 64, 0, stream>>>(A8, A128, fA8_hi, fA8_lo,
                                      fA128_hi, fA128_lo);

  // U = x @ B
  mfma_gemm<<<512, 1024, 0, stream>>>(x, fB_hi, fB_lo, U, 0);

  // chunk local ends: E[c] = scan(0; u over chunk c)
  mfma_rscan<<<NCHUNK / 2, 1024, 0, stream>>>(fA_hi, fA_lo, nullptr, U,
                                              nullptr, E, CHUNK, CHUNK,
                                              NCHUNK, 0, 0);

  // group collect: Sg[g] = scan(0; E over group g) with A^8
  mfma_rscan<<<NGRP / 2, 1024, 0, stream>>>(fA8_hi, fA8_lo, nullptr, E,
                                            nullptr, Sg, GSZ, GSZ, NGRP, 0, 0);

  // top scan: G[0]=h0; G[g+1] = G[g]@A128 + Sg[g]
  mfma_rscan<<<1, 1024, 0, stream>>>(fA128_hi, fA128_lo, h0, Sg,
                                     G, nullptr, NGRP - 1, NGRP, 1, 1, 1);

  // group entries: Hc[g*GSZ]=G[g]; Hc[c+1] = Hc[c]@A8 + E[c]
  mfma_rscan<<<NGRP / 2, 1024, 0, stream>>>(fA8_hi, fA8_lo, G, E,
                                            Hc, nullptr, GSZ - 1, GSZ, NGRP,
                                            0, 1);

  // final chunk scan from true entries; h overwrites U
  mfma_rscan<<<NCHUNK / 2, 1024, 0, stream>>>(fA_hi, fA_lo, Hc, U,
                                              U, nullptr, CHUNK, CHUNK,
                                              NCHUNK, 0, 0);

  // y = h @ C
  mfma_gemm<<<512, 1024, 0, stream>>>(U, fC_hi, fC_lo, y, 1);
}

// Round 6
// 258.757 us; speedup vs baseline: 4.2251x; 1.0451x over previous
//
#include <hip/hip_runtime.h>

// Linear RNN scan: h_t = h_{t-1}@A + x_t@B ; y_t = h_t@C
// B=8, S=4096, IN=STATE=OUT=256.
// MFMA 16x16x32 f16, 2-term split (hi + 2048*lo), f32 accumulate.
// SWAPPED-OPERAND formulation: h_new^T = A^T @ h^T  — resident frags are the
// A-operand (they encode A^T), LDS h-tile is the B-operand. C-layout then gives
// each lane 1 batch-row x 4 consecutive state cols -> contiguous LDS/global IO.
// Scan hierarchy (all levels on the unified MFMA recurrence kernel):
//   chunk level : 512 chunks x 8 steps   (multiplier A)
//   group level : 32 groups x 16 chunks  (multiplier A^8)
//   top level   : 31 steps over groups   (multiplier A^128)

#define SEQ    4096
#define NBATCH 8
#define ND     256
#define CHUNK  8
#define NCHUNK 512
#define GSZ    16
#define NGRP   32
#define LOSC   2048.0f
#define LOINV  (1.0f/2048.0f)

typedef _Float16 fp16_t;
typedef __attribute__((ext_vector_type(8))) _Float16 f16x8;
typedef __attribute__((ext_vector_type(4))) _Float16 f16x4;
typedef __attribute__((ext_vector_type(4))) float f32x4;

// ---------- pack A,B,C into frag arrays (hi/lo f16) ----------
// frag linear index: ((tile*8 + slice)*64 + lane)*8 + j
// value = M[k][n], k = slice*32 + (lane>>4)*8 + j, n = tile*16 + (lane&15)
// (as A-operand these encode M^T rows tile*16..+15)
__global__ __launch_bounds__(64) void prep_frags3(
    const float* __restrict__ A, const float* __restrict__ B,
    const float* __restrict__ C,
    fp16_t* __restrict__ fAh, fp16_t* __restrict__ fAl,
    fp16_t* __restrict__ fBh, fp16_t* __restrict__ fBl,
    fp16_t* __restrict__ fCh, fp16_t* __restrict__ fCl) {
  const int which = blockIdx.x >> 7;
  const int blk   = blockIdx.x & 127;
  const float* M = (which == 0) ? A : (which == 1) ? B : C;
  fp16_t* hi = (which == 0) ? fAh : (which == 1) ? fBh : fCh;
  fp16_t* lo = (which == 0) ? fAl : (which == 1) ? fBl : fCl;
  const int lane = threadIdx.x;
  const int tile = blk >> 3, slice = blk & 7;
  const int n  = tile * 16 + (lane & 15);
  const int k0 = slice * 32 + (lane >> 4) * 8;
  f16x8 vh, vl;
  #pragma unroll
  for (int j = 0; j < 8; ++j) {
    const float v = M[(size_t)(k0 + j) * ND + n];
    const fp16_t h = (fp16_t)v;
    vh[j] = h;
    vl[j] = (fp16_t)((v - (float)h) * LOSC);
  }
  const size_t fo = ((size_t)blk * 64 + lane) * 8;
  *(f16x8*)&hi[fo] = vh;
  *(f16x8*)&lo[fo] = vl;
}

// ---------- pack A8, A128 into frag arrays ----------
__global__ __launch_bounds__(64) void prep_frags2(
    const float* __restrict__ M0, const float* __restrict__ M1,
    fp16_t* __restrict__ h0p, fp16_t* __restrict__ l0p,
    fp16_t* __restrict__ h1p, fp16_t* __restrict__ l1p) {
  const int which = blockIdx.x >> 7;
  const int blk   = blockIdx.x & 127;
  const float* M = (which == 0) ? M0 : M1;
  fp16_t* hi = (which == 0) ? h0p : h1p;
  fp16_t* lo = (which == 0) ? l0p : l1p;
  const int lane = threadIdx.x;
  const int tile = blk >> 3, slice = blk & 7;
  const int n  = tile * 16 + (lane & 15);
  const int k0 = slice * 32 + (lane >> 4) * 8;
  f16x8 vh, vl;
  #pragma unroll
  for (int j = 0; j < 8; ++j) {
    const float v = M[(size_t)(k0 + j) * ND + n];
    const fp16_t h = (fp16_t)v;
    vh[j] = h;
    vl[j] = (fp16_t)((v - (float)h) * LOSC);
  }
  const size_t fo = ((size_t)blk * 64 + lane) * 8;
  *(f16x8*)&hi[fo] = vh;
  *(f16x8*)&lo[fo] = vl;
}

// ---------- MFMA GEMM: Out[m][:] = X[m][:] @ M,  m = s*8+b, M-block = 64 ----------
// Swapped: C[m][n] = (X@M)[xrow = mt*16+n][Mcol = w*16+m]
// mode 0 (xb): X rows remapped from x[b][s][:];  mode 1 (y): Out remapped to y[b][s][:]
__global__ __launch_bounds__(1024, 4) void mfma_gemm(const float* __restrict__ X,
                                                     const fp16_t* __restrict__ Mhi,
                                                     const fp16_t* __restrict__ Mlo,
                                                     float* __restrict__ Out,
                                                     int mode) {
  const int m0   = blockIdx.x * 64;
  const int tid  = threadIdx.x;
  const int lane = tid & 63;
  const int w    = tid >> 6;          // 16 waves, M-col tile w
  const int br   = lane & 15;
  const int akg  = lane >> 4;

  __shared__ fp16_t Xh[64 * ND];      // hi, XOR-swizzled rows
  __shared__ fp16_t Xl[64 * ND];
  char* Xhb = (char*)Xh;
  char* Xlb = (char*)Xl;

  // stage 64 rows of X, converted to hi/lo (once per block)
  {
    const int r0   = tid >> 6;        // 0..15
    const int col0 = (tid & 63) * 4;  // 0..252
    #pragma unroll
    for (int rr = 0; rr < 4; ++rr) {
      const int row = rr * 16 + r0;
      const int m = m0 + row;
      const size_t in_row = (mode == 0)
          ? ((size_t)(m & 7) * SEQ + (m >> 3))
          : (size_t)m;
      const float4 xv = *(const float4*)&X[in_row * ND + col0];
      const float a[4] = {xv.x, xv.y, xv.z, xv.w};
      f16x4 vh, vl;
      #pragma unroll
      for (int j = 0; j < 4; ++j) {
        const fp16_t h = (fp16_t)a[j];
        vh[j] = h;
        vl[j] = (fp16_t)((a[j] - (float)h) * LOSC);
      }
      const int byte = (row * 512 + col0 * 2) ^ ((row & 7) << 4);
      *(f16x4*)(Xhb + byte) = vh;
      *(f16x4*)(Xlb + byte) = vl;
    }
  }

  // resident M^T frags (A-operand) for this wave's M-col tile
  f16x8 MH[8], ML[8];
  #pragma unroll
  for (int s = 0; s < 8; ++s) {
    const size_t fo = (((size_t)w * 8 + s) * 64 + lane) * 8;
    MH[s] = *(const f16x8*)&Mhi[fo];
    ML[s] = *(const f16x8*)&Mlo[fo];
  }
  __syncthreads();

  f32x4 accm[4], accl[4];
  #pragma unroll
  for (int mt = 0; mt < 4; ++mt) {
    accm[mt] = (f32x4)0.0f;
    accl[mt] = (f32x4)0.0f;
  }

  #pragma unroll
  for (int s = 0; s < 8; ++s) {
    #pragma unroll
    for (int mt = 0; mt < 4; ++mt) {
      const int row = mt * 16 + br;
      const int byte = (row * 512 + s * 64 + akg * 16) ^ ((row & 7) << 4);
      const f16x8 bh = *(const f16x8*)(Xhb + byte);
      const f16x8 bl = *(const f16x8*)(Xlb + byte);
      accm[mt] = __builtin_amdgcn_mfma_f32_16x16x32_f16(MH[s], bh, accm[mt], 0, 0, 0);
      accl[mt] = __builtin_amdgcn_mfma_f32_16x16x32_f16(ML[s], bh, accl[mt], 0, 0, 0);
      accl[mt] = __builtin_amdgcn_mfma_f32_16x16x32_f16(MH[s], bl, accl[mt], 0, 0, 0);
    }
  }

  #pragma unroll
  for (int mt = 0; mt < 4; ++mt) {
    const int m = m0 + mt * 16 + br;            // output row (X-row)
    const size_t out_row = (mode == 1)
        ? ((size_t)(m & 7) * SEQ + (m >> 3))
        : (size_t)m;
    float4 o;
    o.x = accm[mt][0] + accl[mt][0] * LOINV;
    o.y = accm[mt][1] + accl[mt][1] * LOINV;
    o.z = accm[mt][2] + accl[mt][2] * LOINV;
    o.w = accm[mt][3] + accl[mt][3] * LOINV;
    *(float4*)&Out[out_row * ND + w * 16 + akg * 4] = o;
  }
}

// ---------- unified MFMA recurrence kernel (swapped operands) ----------
// Each block runs TWO independent 8-row sequences (seq = blockIdx.x*2 + rowgrp).
// For nupd steps: h = h @ Mult + In[(seq*gstride + j)*NB + b].
// Init: null -> zero; init_bcast -> Init[col] (shared); else Init[(seq*NB+b)*ND+col].
// entry_mode=0: OutEach (if set) written at read position (state after step j).
// entry_mode=1: OutEach gets Init at (seq*gstride), state after step j at
//               (seq*gstride + j + 1).
// OutFinal (if set): final state at row (seq*NB+b).
__global__ __launch_bounds__(1024, 4) void mfma_rscan(
    const fp16_t* __restrict__ Mh, const fp16_t* __restrict__ Ml,
    const float* __restrict__ Init,
    const float* In,
    float* OutEach,
    float* __restrict__ OutFinal,
    int nupd, int gstride, int nseq, int init_bcast, int entry_mode) {
  const int seq0 = blockIdx.x * 2;
  const int tid  = threadIdx.x;
  const int lane = tid & 63;
  const int w    = tid >> 6;          // 16 waves, state-col tile w
  const int br   = lane & 15;         // batch row 0..15
  const int akg  = lane >> 4;

  __shared__ fp16_t hH[16 * ND];
  __shared__ fp16_t hL[16 * ND];
  char* hHb = (char*)hH;
  char* hLb = (char*)hL;

  // init h rows
  {
    const int row  = tid >> 6;          // 0..15
    const int col0 = (tid & 63) * 4;
    const int sq = seq0 + (row >> 3);
    const int b  = row & 7;
    float4 v = make_float4(0.f, 0.f, 0.f, 0.f);
    if (Init != nullptr && sq < nseq) {
      const size_t off = init_bcast ? (size_t)col0
                                    : ((size_t)sq * NBATCH + b) * ND + col0;
      v = *(const float4*)&Init[off];
      if (entry_mode && OutEach != nullptr)
        *(float4*)&OutEach[((size_t)sq * gstride * NBATCH + b) * ND + col0] = v;
    }
    const float a[4] = {v.x, v.y, v.z, v.w};
    f16x4 vh, vl;
    #pragma unroll
    for (int j = 0; j < 4; ++j) {
      const fp16_t h = (fp16_t)a[j];
      vh[j] = h;
      vl[j] = (fp16_t)((a[j] - (float)h) * LOSC);
    }
    const int byte = (row * 512 + col0 * 2) ^ ((row & 7) << 4);
    *(f16x4*)(hHb + byte) = vh;
    *(f16x4*)(hLb + byte) = vl;
  }

  // resident A^T frags (A-operand) for this wave's state-col tile
  f16x8 AH[8], AL[8];
  #pragma unroll
  for (int s = 0; s < 8; ++s) {
    const size_t fo = (((size_t)w * 8 + s) * 64 + lane) * 8;
    AH[s] = *(const f16x8*)&Mh[fo];
    AL[s] = *(const f16x8*)&Ml[fo];
  }
  __syncthreads();

  // this lane's output: batch-row br -> (seq, b); 4 consecutive state cols
  const int sq   = seq0 + (br >> 3);
  const int b    = br & 7;
  const bool live = (sq < nseq);
  const int sqc  = live ? sq : (nseq - 1);     // clamp for safe loads
  const int col0 = w * 16 + akg * 4;

  float4 uv = *(const float4*)&In[((size_t)(sqc * gstride) * NBATCH + b) * ND + col0];
  float4 uvn;
  f32x4 res;
  for (int j = 0; j < nupd; ++j) {
    if (j + 1 < nupd)
      uvn = *(const float4*)&In[((size_t)(sqc * gstride + j + 1) * NBATCH + b) * ND + col0];
    f32x4 accm, accl;
    accm[0] = uv.x; accm[1] = uv.y; accm[2] = uv.z; accm[3] = uv.w;
    accl = (f32x4)0.0f;
    #pragma unroll
    for (int s = 0; s < 8; ++s) {
      const int byte = (br * 512 + s * 64 + akg * 16) ^ ((br & 7) << 4);
      const f16x8 bh = *(const f16x8*)(hHb + byte);
      const f16x8 bl = *(const f16x8*)(hLb + byte);
      accm = __builtin_amdgcn_mfma_f32_16x16x32_f16(AH[s], bh, accm, 0, 0, 0);
      accl = __builtin_amdgcn_mfma_f32_16x16x32_f16(AL[s], bh, accl, 0, 0, 0);
      accl = __builtin_amdgcn_mfma_f32_16x16x32_f16(AH[s], bl, accl, 0, 0, 0);
    }
    #pragma unroll
    for (int r = 0; r < 4; ++r) res[r] = accm[r] + accl[r] * LOINV;
    __syncthreads();                  // reads of old h done
    {
      f16x4 vh, vl;
      #pragma unroll
      for (int r = 0; r < 4; ++r) {
        const fp16_t hh = (fp16_t)res[r];
        vh[r] = hh;
        vl[r] = (fp16_t)((res[r] - (float)hh) * LOSC);
      }
      const int wb = (br * 512 + col0 * 2) ^ ((br & 7) << 4);
      *(f16x4*)(hHb + wb) = vh;
      *(f16x4*)(hLb + wb) = vl;
    }
    if (OutEach != nullptr && live) {
      const size_t pos = entry_mode ? (size_t)(sq * gstride + j + 1)
                                    : (size_t)(sq * gstride + j);
      float4 o;
      o.x = res[0]; o.y = res[1]; o.z = res[2]; o.w = res[3];
      *(float4*)&OutEach[(pos * NBATCH + b) * ND + col0] = o;
    }
    uv = uvn;
    __syncthreads();                  // new h visible
  }

  if (OutFinal != nullptr && live) {
    float4 o;
    o.x = res[0]; o.y = res[1]; o.z = res[2]; o.w = res[3];
    *(float4*)&OutFinal[((size_t)sq * NBATCH + b) * ND + col0] = o;
  }
}

// ---------- dense 256x256 f32 GEMM (A-power chain) ----------
__global__ __launch_bounds__(256) void gemm256(const float* __restrict__ X,
                                               const float* __restrict__ Y,
                                               float* __restrict__ Out) {
  const int m0 = blockIdx.x * 4;
  const int n  = threadIdx.x;
  __shared__ float Xs[ND][4];
  #pragma unroll
  for (int r = 0; r < 4; ++r) Xs[n][r] = X[(m0 + r) * ND + n];
  __syncthreads();
  float a0 = 0.f, a1 = 0.f, a2 = 0.f, a3 = 0.f;
  #pragma unroll 8
  for (int k = 0; k < ND; ++k) {
    const float yv = Y[k * ND + n];
    const float4 xv = *(const float4*)&Xs[k][0];
    a0 = fmaf(xv.x, yv, a0);
    a1 = fmaf(xv.y, yv, a1);
    a2 = fmaf(xv.z, yv, a2);
    a3 = fmaf(xv.w, yv, a3);
  }
  Out[(m0 + 0) * ND + n] = a0;
  Out[(m0 + 1) * ND + n] = a1;
  Out[(m0 + 2) * ND + n] = a2;
  Out[(m0 + 3) * ND + n] = a3;
}

extern "C" void kernel_launch(void* const* d_in, const int* in_sizes, int n_in,
                              void* d_out, int out_size, void* d_ws, size_t ws_size,
                              hipStream_t stream) {
  const float* x  = (const float*)d_in[0];
  const float* A  = (const float*)d_in[1];
  const float* Bm = (const float*)d_in[2];
  const float* Cm = (const float*)d_in[3];
  const float* h0 = (const float*)d_in[4];
  float* y = (float*)d_out;

  float* U    = (float*)d_ws;                        // 8,388,608
  float* t0   = U + (size_t)SEQ * NBATCH * ND;       // 65,536 (reused for A8 frags)
  float* t1   = t0 + ND * ND;                        // 65,536 (reused for A128 frags)
  float* A8   = t1 + ND * ND;
  float* A128 = A8 + ND * ND;
  float* E    = A128 + ND * ND;                      // 1,048,576
  float* Sg   = E + (size_t)NCHUNK * NBATCH * ND;    // 65,536
  float* G    = Sg + (size_t)NGRP * NBATCH * ND;     // 65,536
  float* Hc   = G + (size_t)NGRP * NBATCH * ND;      // 1,048,576
  fp16_t* fA_hi = (fp16_t*)(Hc + (size_t)NCHUNK * NBATCH * ND);
  fp16_t* fA_lo = fA_hi + ND * ND;
  fp16_t* fB_hi = fA_lo + ND * ND;
  fp16_t* fB_lo = fB_hi + ND * ND;
  fp16_t* fC_hi = fB_lo + ND * ND;
  fp16_t* fC_lo = fC_hi + ND * ND;
  // frag arrays for A8 / A128 overlaid on dead t0/t1 scratch
  fp16_t* fA8_hi   = (fp16_t*)t0;
  fp16_t* fA8_lo   = fA8_hi + ND * ND;
  fp16_t* fA128_hi = (fp16_t*)t1;
  fp16_t* fA128_lo = fA128_hi + ND * ND;

  // pack A,B,C into fragment arrays
  prep_frags3<<<384, 64, 0, stream>>>(A, Bm, Cm, fA_hi, fA_lo, fB_hi, fB_lo,
                                      fC_hi, fC_lo);

  // A powers (f32): A^8, A^128  (t0/t1 scratch, then freed)
  gemm256<<<64, 256, 0, stream>>>(A,  A,  t0);       // A^2
  gemm256<<<64, 256, 0, stream>>>(t0, t0, t1);       // A^4
  gemm256<<<64, 256, 0, stream>>>(t1, t1, A8);       // A^8
  gemm256<<<64, 256, 0, stream>>>(A8, A8, t0);       // A^16
  gemm256<<<64, 256, 0, stream>>>(t0, t0, t1);       // A^32
  gemm256<<<64, 256, 0, stream>>>(t1, t1, t0);       // A^64
  gemm256<<<64, 256, 0, stream>>>(t0, t0, A128);     // A^128

  // pack A8/A128 into frags (t0/t1 now reusable as the frag storage)
  prep_frags2<<<256, 64, 0, stream>>>(A8, A128, fA8_hi, fA8_lo,
                                      fA128_hi, fA128_lo);

  // U = x @ B
  mfma_gemm<<<512, 1024, 0, stream>>>(x, fB_hi, fB_lo, U, 0);

  // chunk local ends: E[c] = scan(0; u over chunk c)
  mfma_rscan<<<NCHUNK / 2, 1024, 0, stream>>>(fA_hi, fA_lo, nullptr, U,
                                              nullptr, E, CHUNK, CHUNK,
                                              NCHUNK, 0, 0);

  // group collect: Sg[g] = scan(0; E over group g) with A^8
  mfma_rscan<<<NGRP / 2, 1024, 0, stream>>>(fA8_hi, fA8_lo, nullptr, E,
                                            nullptr, Sg, GSZ, GSZ, NGRP, 0, 0);

  // top scan: G[0]=h0; G[g+1] = G[g]@A128 + Sg[g]
  mfma_rscan<<<1, 1024, 0, stream>>>(fA128_hi, fA128_lo, h0, Sg,
                                     G, nullptr, NGRP - 1, NGRP, 1, 1, 1);

  // group entries: Hc[g*GSZ]=G[g]; Hc[c+1] = Hc[c]@A8 + E[c]
  mfma_rscan<<<NGRP / 2, 1024, 0, stream>>>(fA8_hi, fA8_lo, G, E,
                                            Hc, nullptr, GSZ - 1, GSZ, NGRP,
                                            0, 1);

  // final chunk scan from true entries; h overwrites U
  mfma_rscan<<<NCHUNK / 2, 1024, 0, stream>>>(fA_hi, fA_lo, Hc, U,
                                              U, nullptr, CHUNK, CHUNK,
                                              NCHUNK, 0, 0);

  // y = h @ C
  mfma_gemm<<<512, 1024, 0, stream>>>(U, fC_hi, fC_lo, y, 1);
}

// Round 7
// 232.925 us; speedup vs baseline: 4.6936x; 1.1109x over previous
//
#include <hip/hip_runtime.h>

// Linear RNN scan: h_t = h_{t-1}@A + x_t@B ; y_t = h_t@C
// B=8, S=4096, IN=STATE=OUT=256.
// MFMA 16x16x32 f16, 2-term split (hi + 2048*lo), f32 accumulate.
// Swapped operands: h_new^T = A^T @ h^T (frags = A-operand, LDS h = B-operand).
// LDS layout: slice-linear. Per (mt,s) region of 1024B, 64 slots of 16B,
//   slot = ((akg<<4)|br) ^ s.  Inner-loop wave reads cover one full region
//   (dense permutation) -> conflict-free. Double-buffered h: 1 barrier/step.
// Scan hierarchy: chunk 512x8 (A) / group 32x16 (A^8) / top 31 steps (A^128).

#define SEQ    4096
#define NBATCH 8
#define ND     256
#define CHUNK  8
#define NCHUNK 512
#define GSZ    16
#define NGRP   32
#define LOSC   2048.0f
#define LOINV  (1.0f/2048.0f)

typedef _Float16 fp16_t;
typedef __attribute__((ext_vector_type(8))) _Float16 f16x8;
typedef __attribute__((ext_vector_type(4))) _Float16 f16x4;
typedef __attribute__((ext_vector_type(4))) float f32x4;

// ---------- pack A,B,C into frag arrays (hi/lo f16) ----------
// frag linear index: ((tile*8 + slice)*64 + lane)*8 + j
// value = M[k][n], k = slice*32 + (lane>>4)*8 + j, n = tile*16 + (lane&15)
__global__ __launch_bounds__(64) void prep_frags3(
    const float* __restrict__ A, const float* __restrict__ B,
    const float* __restrict__ C,
    fp16_t* __restrict__ fAh, fp16_t* __restrict__ fAl,
    fp16_t* __restrict__ fBh, fp16_t* __restrict__ fBl,
    fp16_t* __restrict__ fCh, fp16_t* __restrict__ fCl) {
  const int which = blockIdx.x >> 7;
  const int blk   = blockIdx.x & 127;
  const float* M = (which == 0) ? A : (which == 1) ? B : C;
  fp16_t* hi = (which == 0) ? fAh : (which == 1) ? fBh : fCh;
  fp16_t* lo = (which == 0) ? fAl : (which == 1) ? fBl : fCl;
  const int lane = threadIdx.x;
  const int tile = blk >> 3, slice = blk & 7;
  const int n  = tile * 16 + (lane & 15);
  const int k0 = slice * 32 + (lane >> 4) * 8;
  f16x8 vh, vl;
  #pragma unroll
  for (int j = 0; j < 8; ++j) {
    const float v = M[(size_t)(k0 + j) * ND + n];
    const fp16_t h = (fp16_t)v;
    vh[j] = h;
    vl[j] = (fp16_t)((v - (float)h) * LOSC);
  }
  const size_t fo = ((size_t)blk * 64 + lane) * 8;
  *(f16x8*)&hi[fo] = vh;
  *(f16x8*)&lo[fo] = vl;
}

// ---------- pack A8, A128 into frag arrays ----------
__global__ __launch_bounds__(64) void prep_frags2(
    const float* __restrict__ M0, const float* __restrict__ M1,
    fp16_t* __restrict__ h0p, fp16_t* __restrict__ l0p,
    fp16_t* __restrict__ h1p, fp16_t* __restrict__ l1p) {
  const int which = blockIdx.x >> 7;
  const int blk   = blockIdx.x & 127;
  const float* M = (which == 0) ? M0 : M1;
  fp16_t* hi = (which == 0) ? h0p : h1p;
  fp16_t* lo = (which == 0) ? l0p : l1p;
  const int lane = threadIdx.x;
  const int tile = blk >> 3, slice = blk & 7;
  const int n  = tile * 16 + (lane & 15);
  const int k0 = slice * 32 + (lane >> 4) * 8;
  f16x8 vh, vl;
  #pragma unroll
  for (int j = 0; j < 8; ++j) {
    const float v = M[(size_t)(k0 + j) * ND + n];
    const fp16_t h = (fp16_t)v;
    vh[j] = h;
    vl[j] = (fp16_t)((v - (float)h) * LOSC);
  }
  const size_t fo = ((size_t)blk * 64 + lane) * 8;
  *(f16x8*)&hi[fo] = vh;
  *(f16x8*)&lo[fo] = vl;
}

// ---------- MFMA GEMM: Out[m][:] = X[m][:] @ M,  m = s*8+b, M-block = 64 ----------
// mode 0 (xb): X rows remapped from x[b][s][:];  mode 1 (y): Out remapped to y[b][s][:]
__global__ __launch_bounds__(1024, 2) void mfma_gemm(const float* __restrict__ X,
                                                     const fp16_t* __restrict__ Mhi,
                                                     const fp16_t* __restrict__ Mlo,
                                                     float* __restrict__ Out,
                                                     int mode) {
  const int m0   = blockIdx.x * 64;
  const int tid  = threadIdx.x;
  const int lane = tid & 63;
  const int w    = tid >> 6;          // 16 waves, M-col tile w
  const int br   = lane & 15;
  const int akg  = lane >> 4;

  __shared__ fp16_t Xh[32 * 512];     // 32 regions x 1024B (slice-linear)
  __shared__ fp16_t Xl[32 * 512];
  char* Xhb = (char*)Xh;
  char* Xlb = (char*)Xl;

  // stage 64 rows of X -> hi/lo, slice-linear layout (fully coalesced global)
  #pragma unroll
  for (int pass = 0; pass < 2; ++pass) {
    const int tau = pass * 1024 + tid;
    const int row = tau >> 5;         // 0..63
    const int sub = tau & 31;
    const int s   = sub >> 2;
    const int ak  = sub & 3;
    const int m = m0 + row;
    const size_t in_row = (mode == 0)
        ? ((size_t)(m & 7) * SEQ + (m >> 3))
        : (size_t)m;
    const float* xp = &X[in_row * ND + s * 32 + ak * 8];
    const float4 x0 = *(const float4*)(xp);
    const float4 x1 = *(const float4*)(xp + 4);
    const float a[8] = {x0.x, x0.y, x0.z, x0.w, x1.x, x1.y, x1.z, x1.w};
    f16x8 vh, vl;
    #pragma unroll
    for (int j = 0; j < 8; ++j) {
      const fp16_t h = (fp16_t)a[j];
      vh[j] = h;
      vl[j] = (fp16_t)((a[j] - (float)h) * LOSC);
    }
    const int off = (((row >> 4) * 8 + s) << 10) +
                    (((ak << 4) | (row & 15)) ^ s) * 16;
    *(f16x8*)(Xhb + off) = vh;
    *(f16x8*)(Xlb + off) = vl;
  }

  // resident M^T frags (A-operand) for this wave's M-col tile
  f16x8 MH[8], ML[8];
  #pragma unroll
  for (int s = 0; s < 8; ++s) {
    const size_t fo = (((size_t)w * 8 + s) * 64 + lane) * 8;
    MH[s] = *(const f16x8*)&Mhi[fo];
    ML[s] = *(const f16x8*)&Mlo[fo];
  }
  __syncthreads();

  f32x4 accm[4], accl[4];
  #pragma unroll
  for (int mt = 0; mt < 4; ++mt) {
    accm[mt] = (f32x4)0.0f;
    accl[mt] = (f32x4)0.0f;
  }

  const int rdslot = (((akg << 4) | br)) * 16;
  #pragma unroll
  for (int s = 0; s < 8; ++s) {
    const int rdoff = (s ^ ((rdslot >> 4) & 0)) ;  // (placeholder keeps formula local)
    #pragma unroll
    for (int mt = 0; mt < 4; ++mt) {
      const int byte = ((mt * 8 + s) << 10) + ((((akg << 4) | br) ^ s) << 4);
      const f16x8 bh = *(const f16x8*)(Xhb + byte);
      const f16x8 bl = *(const f16x8*)(Xlb + byte);
      accm[mt] = __builtin_amdgcn_mfma_f32_16x16x32_f16(MH[s], bh, accm[mt], 0, 0, 0);
      accl[mt] = __builtin_amdgcn_mfma_f32_16x16x32_f16(ML[s], bh, accl[mt], 0, 0, 0);
      accl[mt] = __builtin_amdgcn_mfma_f32_16x16x32_f16(MH[s], bl, accl[mt], 0, 0, 0);
    }
    (void)rdoff;
  }

  #pragma unroll
  for (int mt = 0; mt < 4; ++mt) {
    const int m = m0 + mt * 16 + br;            // output row (X-row)
    const size_t out_row = (mode == 1)
        ? ((size_t)(m & 7) * SEQ + (m >> 3))
        : (size_t)m;
    float4 o;
    o.x = accm[mt][0] + accl[mt][0] * LOINV;
    o.y = accm[mt][1] + accl[mt][1] * LOINV;
    o.z = accm[mt][2] + accl[mt][2] * LOINV;
    o.w = accm[mt][3] + accl[mt][3] * LOINV;
    *(float4*)&Out[out_row * ND + w * 16 + akg * 4] = o;
  }
}

// ---------- unified MFMA recurrence kernel (swapped operands) ----------
// Each block runs TWO independent 8-row sequences (seq = blockIdx.x*2 + rowgrp).
// For nupd steps: h = h @ Mult + In[(seq*gstride + j)*NB + b].
// Init: null -> zero; init_bcast -> Init[col]; else Init[(seq*NB+b)*ND+col].
// entry_mode=0: OutEach written at (seq*gstride + j).
// entry_mode=1: OutEach gets Init at (seq*gstride), step-j state at (.. + j + 1).
// OutFinal: final state at row (seq*NB+b).
__global__ __launch_bounds__(1024, 2) void mfma_rscan(
    const fp16_t* __restrict__ Mh, const fp16_t* __restrict__ Ml,
    const float* __restrict__ Init,
    const float* In,
    float* OutEach,
    float* __restrict__ OutFinal,
    int nupd, int gstride, int nseq, int init_bcast, int entry_mode) {
  const int seq0 = blockIdx.x * 2;
  const int tid  = threadIdx.x;
  const int lane = tid & 63;
  const int w    = tid >> 6;          // 16 waves, state-col tile w
  const int br   = lane & 15;         // batch row 0..15
  const int akg  = lane >> 4;

  __shared__ fp16_t hH[2][8 * 512];   // [buf][slice-linear 8KB]
  __shared__ fp16_t hL[2][8 * 512];

  // init h (buf 0), slice-linear
  {
    const int task = tid >> 1;        // 0..511
    const int half = tid & 1;
    const int row  = task & 15;
    const int s    = (task >> 4) & 7;
    const int ak   = task >> 7;       // 0..3
    const int sq = seq0 + (row >> 3);
    const int b  = row & 7;
    const int c0 = s * 32 + ak * 8 + half * 4;
    float4 v = make_float4(0.f, 0.f, 0.f, 0.f);
    if (Init != nullptr && sq < nseq) {
      const size_t off = init_bcast ? (size_t)c0
                                    : ((size_t)sq * NBATCH + b) * ND + c0;
      v = *(const float4*)&Init[off];
      if (entry_mode && OutEach != nullptr)
        *(float4*)&OutEach[((size_t)sq * gstride * NBATCH + b) * ND + c0] = v;
    }
    const float a[4] = {v.x, v.y, v.z, v.w};
    f16x4 vh, vl;
    #pragma unroll
    for (int j = 0; j < 4; ++j) {
      const fp16_t h = (fp16_t)a[j];
      vh[j] = h;
      vl[j] = (fp16_t)((a[j] - (float)h) * LOSC);
    }
    const int off = (s << 10) + ((((ak << 4) | row) ^ s) << 4) + half * 8;
    *(f16x4*)((char*)hH[0] + off) = vh;
    *(f16x4*)((char*)hL[0] + off) = vl;
  }

  // resident A^T frags (A-operand) for this wave's state-col tile
  f16x8 AH[8], AL[8];
  #pragma unroll
  for (int s = 0; s < 8; ++s) {
    const size_t fo = (((size_t)w * 8 + s) * 64 + lane) * 8;
    AH[s] = *(const f16x8*)&Mh[fo];
    AL[s] = *(const f16x8*)&Ml[fo];
  }
  __syncthreads();

  // this lane's output: batch-row br -> (seq, b); 4 consecutive state cols
  const int sq   = seq0 + (br >> 3);
  const int b    = br & 7;
  const bool live = (sq < nseq);
  const int sqc  = live ? sq : (nseq - 1);     // clamp for safe loads
  const int col0 = w * 16 + akg * 4;

  // precomputed LDS offsets
  int rdoff[8];
  #pragma unroll
  for (int s = 0; s < 8; ++s)
    rdoff[s] = (s << 10) + ((((akg << 4) | br) ^ s) << 4);
  const int sw   = col0 >> 5;
  const int akr  = (col0 >> 3) & 3;
  const int wroff = (sw << 10) + ((((akr << 4) | br) ^ sw) << 4) + (col0 & 7) * 2;

  float4 uv = *(const float4*)&In[((size_t)(sqc * gstride) * NBATCH + b) * ND + col0];
  float4 uvn;
  f32x4 res;
  int p = 0;
  for (int j = 0; j < nupd; ++j) {
    if (j + 1 < nupd)
      uvn = *(const float4*)&In[((size_t)(sqc * gstride + j + 1) * NBATCH + b) * ND + col0];
    const char* rH = (const char*)hH[p];
    const char* rL = (const char*)hL[p];
    f32x4 accm, acclA, acclB;
    accm[0] = uv.x; accm[1] = uv.y; accm[2] = uv.z; accm[3] = uv.w;
    acclA = (f32x4)0.0f;
    acclB = (f32x4)0.0f;
    #pragma unroll
    for (int s = 0; s < 8; ++s) {
      const f16x8 bh = *(const f16x8*)(rH + rdoff[s]);
      const f16x8 bl = *(const f16x8*)(rL + rdoff[s]);
      accm  = __builtin_amdgcn_mfma_f32_16x16x32_f16(AH[s], bh, accm,  0, 0, 0);
      acclA = __builtin_amdgcn_mfma_f32_16x16x32_f16(AL[s], bh, acclA, 0, 0, 0);
      acclB = __builtin_amdgcn_mfma_f32_16x16x32_f16(AH[s], bl, acclB, 0, 0, 0);
    }
    #pragma unroll
    for (int r = 0; r < 4; ++r) res[r] = accm[r] + (acclA[r] + acclB[r]) * LOINV;
    // write new h into the OTHER buffer (no barrier needed before writes)
    {
      f16x4 vh, vl;
      #pragma unroll
      for (int r = 0; r < 4; ++r) {
        const fp16_t hh = (fp16_t)res[r];
        vh[r] = hh;
        vl[r] = (fp16_t)((res[r] - (float)hh) * LOSC);
      }
      *(f16x4*)((char*)hH[p ^ 1] + wroff) = vh;
      *(f16x4*)((char*)hL[p ^ 1] + wroff) = vl;
    }
    if (OutEach != nullptr && live) {
      const size_t pos = entry_mode ? (size_t)(sq * gstride + j + 1)
                                    : (size_t)(sq * gstride + j);
      float4 o;
      o.x = res[0]; o.y = res[1]; o.z = res[2]; o.w = res[3];
      *(float4*)&OutEach[(pos * NBATCH + b) * ND + col0] = o;
    }
    uv = uvn;
    p ^= 1;
    __syncthreads();                  // new h visible; old buf free for reuse
  }

  if (OutFinal != nullptr && live) {
    float4 o;
    o.x = res[0]; o.y = res[1]; o.z = res[2]; o.w = res[3];
    *(float4*)&OutFinal[((size_t)sq * NBATCH + b) * ND + col0] = o;
  }
}

// ---------- dense 256x256 f32 GEMM (A-power chain) ----------
__global__ __launch_bounds__(256) void gemm256(const float* __restrict__ X,
                                               const float* __restrict__ Y,
                                               float* __restrict__ Out) {
  const int m0 = blockIdx.x * 4;
  const int n  = threadIdx.x;
  __shared__ float Xs[ND][4];
  #pragma unroll
  for (int r = 0; r < 4; ++r) Xs[n][r] = X[(m0 + r) * ND + n];
  __syncthreads();
  float a0 = 0.f, a1 = 0.f, a2 = 0.f, a3 = 0.f;
  #pragma unroll 8
  for (int k = 0; k < ND; ++k) {
    const float yv = Y[k * ND + n];
    const float4 xv = *(const float4*)&Xs[k][0];
    a0 = fmaf(xv.x, yv, a0);
    a1 = fmaf(xv.y, yv, a1);
    a2 = fmaf(xv.z, yv, a2);
    a3 = fmaf(xv.w, yv, a3);
  }
  Out[(m0 + 0) * ND + n] = a0;
  Out[(m0 + 1) * ND + n] = a1;
  Out[(m0 + 2) * ND + n] = a2;
  Out[(m0 + 3) * ND + n] = a3;
}

extern "C" void kernel_launch(void* const* d_in, const int* in_sizes, int n_in,
                              void* d_out, int out_size, void* d_ws, size_t ws_size,
                              hipStream_t stream) {
  const float* x  = (const float*)d_in[0];
  const float* A  = (const float*)d_in[1];
  const float* Bm = (const float*)d_in[2];
  const float* Cm = (const float*)d_in[3];
  const float* h0 = (const float*)d_in[4];
  float* y = (float*)d_out;

  float* U    = (float*)d_ws;                        // 8,388,608
  float* t0   = U + (size_t)SEQ * NBATCH * ND;       // 65,536 (reused for A8 frags)
  float* t1   = t0 + ND * ND;                        // 65,536 (reused for A128 frags)
  float* A8   = t1 + ND * ND;
  float* A128 = A8 + ND * ND;
  float* E    = A128 + ND * ND;                      // 1,048,576
  float* Sg   = E + (size_t)NCHUNK * NBATCH * ND;    // 65,536
  float* G    = Sg + (size_t)NGRP * NBATCH * ND;     // 65,536
  float* Hc   = G + (size_t)NGRP * NBATCH * ND;      // 1,048,576
  fp16_t* fA_hi = (fp16_t*)(Hc + (size_t)NCHUNK * NBATCH * ND);
  fp16_t* fA_lo = fA_hi + ND * ND;
  fp16_t* fB_hi = fA_lo + ND * ND;
  fp16_t* fB_lo = fB_hi + ND * ND;
  fp16_t* fC_hi = fB_lo + ND * ND;
  fp16_t* fC_lo = fC_hi + ND * ND;
  // frag arrays for A8 / A128 overlaid on dead t0/t1 scratch
  fp16_t* fA8_hi   = (fp16_t*)t0;
  fp16_t* fA8_lo   = fA8_hi + ND * ND;
  fp16_t* fA128_hi = (fp16_t*)t1;
  fp16_t* fA128_lo = fA128_hi + ND * ND;

  // pack A,B,C into fragment arrays
  prep_frags3<<<384, 64, 0, stream>>>(A, Bm, Cm, fA_hi, fA_lo, fB_hi, fB_lo,
                                      fC_hi, fC_lo);

  // A powers (f32): A^8, A^128  (t0/t1 scratch, then freed)
  gemm256<<<64, 256, 0, stream>>>(A,  A,  t0);       // A^2
  gemm256<<<64, 256, 0, stream>>>(t0, t0, t1);       // A^4
  gemm256<<<64, 256, 0, stream>>>(t1, t1, A8);       // A^8
  gemm256<<<64, 256, 0, stream>>>(A8, A8, t0);       // A^16
  gemm256<<<64, 256, 0, stream>>>(t0, t0, t1);       // A^32
  gemm256<<<64, 256, 0, stream>>>(t1, t1, t0);       // A^64
  gemm256<<<64, 256, 0, stream>>>(t0, t0, A128);     // A^128

  // pack A8/A128 into frags (t0/t1 now reusable as the frag storage)
  prep_frags2<<<256, 64, 0, stream>>>(A8, A128, fA8_hi, fA8_lo,
                                      fA128_hi, fA128_lo);

  // U = x @ B
  mfma_gemm<<<512, 1024, 0, stream>>>(x, fB_hi, fB_lo, U, 0);

  // chunk local ends: E[c] = scan(0; u over chunk c)
  mfma_rscan<<<NCHUNK / 2, 1024, 0, stream>>>(fA_hi, fA_lo, nullptr, U,
                                              nullptr, E, CHUNK, CHUNK,
                                              NCHUNK, 0, 0);

  // group collect: Sg[g] = scan(0; E over group g) with A^8
  mfma_rscan<<<NGRP / 2, 1024, 0, stream>>>(fA8_hi, fA8_lo, nullptr, E,
                                            nullptr, Sg, GSZ, GSZ, NGRP, 0, 0);

  // top scan: G[0]=h0; G[g+1] = G[g]@A128 + Sg[g]
  mfma_rscan<<<1, 1024, 0, stream>>>(fA128_hi, fA128_lo, h0, Sg,
                                     G, nullptr, NGRP - 1, NGRP, 1, 1, 1);

  // group entries: Hc[g*GSZ]=G[g]; Hc[c+1] = Hc[c]@A8 + E[c]
  mfma_rscan<<<NGRP / 2, 1024, 0, stream>>>(fA8_hi, fA8_lo, G, E,
                                            Hc, nullptr, GSZ - 1, GSZ, NGRP,
                                            0, 1);

  // final chunk scan from true entries; h overwrites U
  mfma_rscan<<<NCHUNK / 2, 1024, 0, stream>>>(fA_hi, fA_lo, Hc, U,
                                              U, nullptr, CHUNK, CHUNK,
                                              NCHUNK, 0, 0);

  // y = h @ C
  mfma_gemm<<<512, 1024, 0, stream>>>(U, fC_hi, fC_lo, y, 1);
}